// Round 6
// baseline (121.501 us; speedup 1.0000x reference)
//
#include <hip/hip_runtime.h>
#include <cmath>

#define B_ 8
#define S_ 512
#define D_ 512
#define H_ 1024
#define E_ 8
#define NT_ (B_*S_)   // 4096 tokens
#define TM 16         // tokens per tile (fallback path)

typedef __attribute__((ext_vector_type(8))) short short8v;
typedef __attribute__((ext_vector_type(4))) float f32x4;

__device__ inline unsigned short f2bf(float f) {
    union { float f; unsigned u; } a; a.f = f;
    unsigned u = a.u;
    return (unsigned short)((u + 0x7FFF + ((u >> 16) & 1)) >> 16);  // RNE
}

// ======================= TIER A (main path) =======================

// ---- prep_fused ----
// blocks 0..1023   : out = x, xbf = bf16(x), per-token gating (no atomics)
// blocks 1024..5119: direct fragment-native weight repack, one 1KB chunk/wave,
//                    zero LDS. chunk(F,kidx): lane l=(g*16+m), short j <-
//                    W[k=kidx*32+g*8+j][n=F*16+m]. Loads: 8x scalar dword,
//                    each wave-load = 4 rows x 64B contiguous (fully coalesced).
__global__ __launch_bounds__(256) void prep_fused(
    const float* __restrict__ x, const int* __restrict__ mask,
    const float* __restrict__ wg,
    const float* __restrict__ W1, const float* __restrict__ W2,
    float* __restrict__ out, unsigned short* __restrict__ xbf,
    uchar2* __restrict__ tokE, float2* __restrict__ tokG,
    unsigned short* __restrict__ W1S, unsigned short* __restrict__ W2S)
{
    const int tid = threadIdx.x, wave = tid >> 6, lane = tid & 63;
    const int bid = blockIdx.x;

    if (bid < 1024) {
        // -------- x pass + gating: one wave per token --------
        const int t = bid * 4 + wave;
        const float4* xr = (const float4*)(x + ((size_t)t << 9));
        const float4 v0 = xr[lane];
        const float4 v1 = xr[lane + 64];
        float4* orow = (float4*)(out + ((size_t)t << 9));
        orow[lane] = v0; orow[lane + 64] = v1;
        union { unsigned short u[4]; uint2 w; } pa, pb;
        pa.u[0]=f2bf(v0.x); pa.u[1]=f2bf(v0.y); pa.u[2]=f2bf(v0.z); pa.u[3]=f2bf(v0.w);
        pb.u[0]=f2bf(v1.x); pb.u[1]=f2bf(v1.y); pb.u[2]=f2bf(v1.z); pb.u[3]=f2bf(v1.w);
        uint2* xrow = (uint2*)(xbf + ((size_t)t << 9));
        xrow[lane] = pa.w; xrow[lane + 64] = pb.w;

        float acc[E_];
#pragma unroll
        for (int e = 0; e < E_; ++e) acc[e] = 0.f;
        const int d0 = lane * 4;
#pragma unroll
        for (int dd = 0; dd < 4; ++dd) {
            const float xa = (&v0.x)[dd], xb = (&v1.x)[dd];
            const float4 wa0 = *(const float4*)(wg + (size_t)(d0 + dd) * 8);
            const float4 wa1 = *(const float4*)(wg + (size_t)(d0 + dd) * 8 + 4);
            const float4 wb0 = *(const float4*)(wg + (size_t)(256 + d0 + dd) * 8);
            const float4 wb1 = *(const float4*)(wg + (size_t)(256 + d0 + dd) * 8 + 4);
            acc[0] += xa * wa0.x + xb * wb0.x;
            acc[1] += xa * wa0.y + xb * wb0.y;
            acc[2] += xa * wa0.z + xb * wb0.z;
            acc[3] += xa * wa0.w + xb * wb0.w;
            acc[4] += xa * wa1.x + xb * wb1.x;
            acc[5] += xa * wa1.y + xb * wb1.y;
            acc[6] += xa * wa1.z + xb * wb1.z;
            acc[7] += xa * wa1.w + xb * wb1.w;
        }
#pragma unroll
        for (int e = 0; e < E_; ++e) {
            float v = acc[e];
#pragma unroll
            for (int off = 32; off > 0; off >>= 1) v += __shfl_xor(v, off, 64);
            acc[e] = v;
        }
        if (lane == 0) {
            if (mask[t] != 0) {
                int i0 = 0; float v0m = acc[0];
#pragma unroll
                for (int e = 1; e < E_; ++e) if (acc[e] > v0m) { v0m = acc[e]; i0 = e; }
                int i1 = -1; float v1m = -INFINITY;
#pragma unroll
                for (int e = 0; e < E_; ++e) if (e != i0 && acc[e] > v1m) { v1m = acc[e]; i1 = e; }
                const float ex = __expf(v1m - v0m);
                const float denom = 1.f + ex;
                tokE[t] = make_uchar2((unsigned char)i0, (unsigned char)i1);
                tokG[t] = make_float2(1.f / denom, ex / denom);
            } else {
                tokE[t] = make_uchar2(255, 255);
            }
        }
        return;
    }

    // -------- direct repack: one chunk per wave --------
    const int c = (bid - 1024) * 4 + wave;      // 0..16383
    const int g = lane >> 4, m = lane & 15;
    const float* src; unsigned short* dst; int stride;
    if (c < 8192) {
        const int e = c >> 10, rem = c & 1023;           // W1: K32=16
        const int F = rem >> 4, kidx = rem & 15;
        src = W1 + ((size_t)e << 19) + (size_t)(kidx * 32 + g * 8) * H_ + F * 16 + m;
        stride = H_;
        dst = W1S + ((size_t)e << 19) + ((size_t)rem << 9) + lane * 8;
    } else {
        const int c2 = c - 8192;
        const int e = c2 >> 10, rem = c2 & 1023;         // W2: K32=32
        const int F = rem >> 5, kidx = rem & 31;
        src = W2 + ((size_t)e << 19) + (size_t)(kidx * 32 + g * 8) * D_ + F * 16 + m;
        stride = D_;
        dst = W2S + ((size_t)e << 19) + ((size_t)rem << 9) + lane * 8;
    }
    float v[8];
#pragma unroll
    for (int j = 0; j < 8; ++j) v[j] = src[(size_t)j * stride];
    union { unsigned short u[8]; uint4 q; } p;
#pragma unroll
    for (int j = 0; j < 8; ++j) p.u[j] = f2bf(v[j]);
    *(uint4*)dst = p.q;
}

// ---- build_kernel: single block, deterministic counting sort (no atomics) ----
__global__ __launch_bounds__(256) void build_kernel(
    const uchar2* __restrict__ tokE, const float2* __restrict__ tokG,
    int* __restrict__ counts, int* __restrict__ lists, float* __restrict__ gvals)
{
    __shared__ int waveTot[4][E_];
    __shared__ int waveBase[4][E_];
    const int tid = threadIdx.x;
    const int lane = tid & 63, wave = tid >> 6;
    int h[E_];
#pragma unroll
    for (int e = 0; e < E_; ++e) h[e] = 0;
#pragma unroll
    for (int j = 0; j < 16; ++j) {
        const uchar2 ee = tokE[tid * 16 + j];
#pragma unroll
        for (int e = 0; e < E_; ++e) h[e] += (ee.x == e) + (ee.y == e);
    }
    int pre[E_];
#pragma unroll
    for (int e = 0; e < E_; ++e) {
        int v = h[e];
#pragma unroll
        for (int off = 1; off < 64; off <<= 1) {
            const int o = __shfl_up(v, off, 64);
            if (lane >= off) v += o;
        }
        pre[e] = v - h[e];
        if (lane == 63) waveTot[wave][e] = v;
    }
    __syncthreads();
    if (tid < E_) {
        int s = 0;
#pragma unroll
        for (int w = 0; w < 4; ++w) { const int v = waveTot[w][tid]; waveBase[w][tid] = s; s += v; }
        counts[tid] = s;
    }
    __syncthreads();
    int base[E_], cnt[E_];
#pragma unroll
    for (int e = 0; e < E_; ++e) { base[e] = waveBase[wave][e] + pre[e]; cnt[e] = 0; }
#pragma unroll
    for (int j = 0; j < 16; ++j) {
        const int t = tid * 16 + j;
        const uchar2 ee = tokE[t];
        if (ee.x == 255) continue;
        const float2 gg = tokG[t];
#pragma unroll
        for (int e = 0; e < E_; ++e) {
            if (ee.x == e) { const int s = base[e] + cnt[e]; lists[e * NT_ + s] = t; gvals[e * NT_ + s] = gg.x; cnt[e]++; }
            if (ee.y == e) { const int s = base[e] + cnt[e]; lists[e * NT_ + s] = t; gvals[e * NT_ + s] = gg.y; cnt[e]++; }
        }
    }
}

// ---- per-block (expert, tile) mapping from counts prefix ----
__device__ inline bool find_tile(const int* __restrict__ counts, int tflat,
                                 int& e, int& t0, int& off, int& n_e)
{
    int cum = 0, offacc = 0; e = -1;
#pragma unroll
    for (int i = 0; i < E_; ++i) {
        const int c = counts[i];
        const int t = (c + 31) >> 5;
        if (e < 0 && tflat < cum + t) { e = i; t0 = (tflat - cum) << 5; off = offacc; n_e = c; }
        cum += t; offacc += c;
    }
    return e >= 0;
}

// ---- stage1: H[slot][h] = relu(Xbf[tok] @ W1 + b1), streaming MFMA ----
__global__ __launch_bounds__(256) void stage1_kernel(
    const unsigned short* __restrict__ xbf,
    const unsigned short* __restrict__ W1S, const float* __restrict__ b1,
    const int* __restrict__ counts, const int* __restrict__ lists,
    unsigned short* __restrict__ Hbuf)
{
    const int nb = blockIdx.x & 3;
    const int tflat = blockIdx.x >> 2;
    int e, t0, off, n_e;
    if (!find_tile(counts, tflat, e, t0, off, n_e)) return;
    const int mact = min(32, n_e - t0);
    __shared__ int tks[32];
    const int tid = threadIdx.x;
    if (tid < 32) tks[tid] = lists[e * NT_ + t0 + min(tid, mact - 1)];
    __syncthreads();

    const int wave = tid >> 6, lane = tid & 63, m = lane & 15, g = lane >> 4;
    const int colbase = nb * 256 + wave * 64;

    const unsigned short* a0p = xbf + ((size_t)tks[m] << 9) + (g << 3);
    const unsigned short* a1p = xbf + ((size_t)tks[16 + m] << 9) + (g << 3);
    const unsigned short* Bb = W1S + ((size_t)e << 19)
                             + ((size_t)(nb * 16 + wave * 4) << 13) + (lane << 3);

    f32x4 acc[2][4];
#pragma unroll
    for (int i = 0; i < 2; ++i)
#pragma unroll
        for (int f = 0; f < 4; ++f) acc[i][f] = (f32x4){0.f, 0.f, 0.f, 0.f};

#pragma unroll 2
    for (int kk = 0; kk < 16; ++kk) {
        const short8v a0 = *(const short8v*)(a0p + (kk << 5));
        const short8v a1 = *(const short8v*)(a1p + (kk << 5));
        const short8v b0  = *(const short8v*)(Bb + (kk << 9));
        const short8v b1v = *(const short8v*)(Bb + (1 << 13) + (kk << 9));
        const short8v b2v = *(const short8v*)(Bb + (2 << 13) + (kk << 9));
        const short8v b3  = *(const short8v*)(Bb + (3 << 13) + (kk << 9));
        acc[0][0] = __builtin_amdgcn_mfma_f32_16x16x32_bf16(a0, b0,  acc[0][0], 0, 0, 0);
        acc[1][0] = __builtin_amdgcn_mfma_f32_16x16x32_bf16(a1, b0,  acc[1][0], 0, 0, 0);
        acc[0][1] = __builtin_amdgcn_mfma_f32_16x16x32_bf16(a0, b1v, acc[0][1], 0, 0, 0);
        acc[1][1] = __builtin_amdgcn_mfma_f32_16x16x32_bf16(a1, b1v, acc[1][1], 0, 0, 0);
        acc[0][2] = __builtin_amdgcn_mfma_f32_16x16x32_bf16(a0, b2v, acc[0][2], 0, 0, 0);
        acc[1][2] = __builtin_amdgcn_mfma_f32_16x16x32_bf16(a1, b2v, acc[1][2], 0, 0, 0);
        acc[0][3] = __builtin_amdgcn_mfma_f32_16x16x32_bf16(a0, b3,  acc[0][3], 0, 0, 0);
        acc[1][3] = __builtin_amdgcn_mfma_f32_16x16x32_bf16(a1, b3,  acc[1][3], 0, 0, 0);
    }

#pragma unroll
    for (int f = 0; f < 4; ++f) {
        const int col = colbase + f * 16 + m;
        const float bias = b1[(e << 10) + col];
#pragma unroll
        for (int i = 0; i < 2; ++i)
#pragma unroll
            for (int r = 0; r < 4; ++r) {
                const int row = i * 16 + g * 4 + r;
                if (row < mact)
                    Hbuf[((size_t)(off + t0 + row) << 10) + col] =
                        f2bf(fmaxf(acc[i][f][r] + bias, 0.f));
            }
    }
}

// ---- stage2: out[tok] += gate * (H[slot] @ W2 + b2), streaming MFMA ----
__global__ __launch_bounds__(256) void stage2_kernel(
    const unsigned short* __restrict__ Hbuf,
    const unsigned short* __restrict__ W2S, const float* __restrict__ b2,
    const int* __restrict__ counts, const int* __restrict__ lists,
    const float* __restrict__ gvals, float* __restrict__ out)
{
    const int nb = blockIdx.x & 1;
    const int tflat = blockIdx.x >> 1;
    int e, t0, off, n_e;
    if (!find_tile(counts, tflat, e, t0, off, n_e)) return;
    const int mact = min(32, n_e - t0);
    __shared__ int tks[32];
    __shared__ float gsh[32];
    const int tid = threadIdx.x;
    if (tid < 32) {
        const int idx = min(tid, mact - 1);
        tks[tid] = lists[e * NT_ + t0 + idx];
        gsh[tid] = gvals[e * NT_ + t0 + idx];
    }
    __syncthreads();

    const int wave = tid >> 6, lane = tid & 63, m = lane & 15, g = lane >> 4;
    const int colbase = nb * 256 + wave * 64;

    const unsigned short* a0p = Hbuf + ((size_t)(off + t0 + m) << 10) + (g << 3);
    const unsigned short* a1p = Hbuf + ((size_t)(off + t0 + 16 + m) << 10) + (g << 3);
    const unsigned short* Bb = W2S + ((size_t)e << 19)
                             + ((size_t)(nb * 16 + wave * 4) << 14) + (lane << 3);

    f32x4 acc[2][4];
#pragma unroll
    for (int i = 0; i < 2; ++i)
#pragma unroll
        for (int f = 0; f < 4; ++f) acc[i][f] = (f32x4){0.f, 0.f, 0.f, 0.f};

#pragma unroll 2
    for (int kk = 0; kk < 32; ++kk) {
        const short8v a0 = *(const short8v*)(a0p + (kk << 5));
        const short8v a1 = *(const short8v*)(a1p + (kk << 5));
        const short8v b0  = *(const short8v*)(Bb + (kk << 9));
        const short8v b1v = *(const short8v*)(Bb + (1 << 14) + (kk << 9));
        const short8v b2v = *(const short8v*)(Bb + (2 << 14) + (kk << 9));
        const short8v b3  = *(const short8v*)(Bb + (3 << 14) + (kk << 9));
        acc[0][0] = __builtin_amdgcn_mfma_f32_16x16x32_bf16(a0, b0,  acc[0][0], 0, 0, 0);
        acc[1][0] = __builtin_amdgcn_mfma_f32_16x16x32_bf16(a1, b0,  acc[1][0], 0, 0, 0);
        acc[0][1] = __builtin_amdgcn_mfma_f32_16x16x32_bf16(a0, b1v, acc[0][1], 0, 0, 0);
        acc[1][1] = __builtin_amdgcn_mfma_f32_16x16x32_bf16(a1, b1v, acc[1][1], 0, 0, 0);
        acc[0][2] = __builtin_amdgcn_mfma_f32_16x16x32_bf16(a0, b2v, acc[0][2], 0, 0, 0);
        acc[1][2] = __builtin_amdgcn_mfma_f32_16x16x32_bf16(a1, b2v, acc[1][2], 0, 0, 0);
        acc[0][3] = __builtin_amdgcn_mfma_f32_16x16x32_bf16(a0, b3,  acc[0][3], 0, 0, 0);
        acc[1][3] = __builtin_amdgcn_mfma_f32_16x16x32_bf16(a1, b3,  acc[1][3], 0, 0, 0);
    }

#pragma unroll
    for (int f = 0; f < 4; ++f) {
        const int col = colbase + f * 16 + m;
        const float bias = b2[(e << 9) + col];
#pragma unroll
        for (int i = 0; i < 2; ++i)
#pragma unroll
            for (int r = 0; r < 4; ++r) {
                const int row = i * 16 + g * 4 + r;
                if (row < mact)
                    atomicAdd(out + ((size_t)tks[row] << 9) + col,
                              (acc[i][f][r] + bias) * gsh[row]);
            }
    }
}

// ======================= TIER B/C fallbacks =======================

__global__ __launch_bounds__(256) void gating_kernel(
    const float* __restrict__ x, const int* __restrict__ mask,
    const float* __restrict__ wg, int* __restrict__ counts,
    int* __restrict__ lists, float* __restrict__ gvals)
{
    const int wave = threadIdx.x >> 6;
    const int lane = threadIdx.x & 63;
    const int t = blockIdx.x * 4 + wave;
    const float* xr = x + (size_t)t * D_;
    float acc[E_];
#pragma unroll
    for (int e = 0; e < E_; ++e) acc[e] = 0.f;
    for (int d = lane; d < D_; d += 64) {
        const float xv = xr[d];
        const float* wr = wg + (size_t)d * E_;
#pragma unroll
        for (int e = 0; e < E_; ++e) acc[e] += xv * wr[e];
    }
#pragma unroll
    for (int e = 0; e < E_; ++e) {
        float v = acc[e];
#pragma unroll
        for (int off = 32; off > 0; off >>= 1) v += __shfl_down(v, off, 64);
        acc[e] = v;
    }
    if (lane == 0 && mask[t] != 0) {
        int i0 = 0; float v0 = acc[0];
#pragma unroll
        for (int e = 1; e < E_; ++e) if (acc[e] > v0) { v0 = acc[e]; i0 = e; }
        int i1 = -1; float v1 = -INFINITY;
#pragma unroll
        for (int e = 0; e < E_; ++e) if (e != i0 && acc[e] > v1) { v1 = acc[e]; i1 = e; }
        const float ex = __expf(v1 - v0);
        const float denom = 1.f + ex;
        const int p0 = atomicAdd(&counts[i0], 1);
        lists[i0 * NT_ + p0] = t; gvals[i0 * NT_ + p0] = 1.f / denom;
        const int p1 = atomicAdd(&counts[i1], 1);
        lists[i1 * NT_ + p1] = t; gvals[i1 * NT_ + p1] = ex / denom;
    }
}

__global__ __launch_bounds__(256) void init_out_kernel(
    const float* __restrict__ x, float* __restrict__ out)
{
    const size_t i = (size_t)blockIdx.x * blockDim.x + threadIdx.x;
    ((float4*)out)[i] = ((const float4*)x)[i];
}

__global__ __launch_bounds__(256) void transpose_cvt(
    const float* __restrict__ src, unsigned short* __restrict__ dst, int R, int C)
{
    __shared__ unsigned short t[64][72];
    const float* s = src + (size_t)blockIdx.z * R * C;
    unsigned short* d = dst + (size_t)blockIdx.z * R * C;
    const int r0 = blockIdx.y * 64, c0 = blockIdx.x * 64;
    const int tc = threadIdx.x & 63;
    const int tr = threadIdx.x >> 6;
#pragma unroll
    for (int i = 0; i < 16; ++i) {
        const int r = tr + i * 4;
        t[r][tc] = f2bf(s[(size_t)(r0 + r) * C + c0 + tc]);
    }
    __syncthreads();
    const int c = threadIdx.x >> 2;
    const int ch = threadIdx.x & 3;
#pragma unroll
    for (int half = 0; half < 2; ++half) {
        union { unsigned short u[8]; uint4 v; } p;
#pragma unroll
        for (int k = 0; k < 8; ++k) p.u[k] = t[ch * 16 + half * 8 + k][c];
        *(uint4*)(d + (size_t)(c0 + c) * R + r0 + ch * 16 + half * 8) = p.v;
    }
}

__global__ __launch_bounds__(256) void expert_mfma(
    const float* __restrict__ x,
    const unsigned short* __restrict__ W1T, const float* __restrict__ b1,
    const unsigned short* __restrict__ W2T, const float* __restrict__ b2,
    const int* __restrict__ counts, const int* __restrict__ lists,
    const float* __restrict__ gvals, float* __restrict__ out)
{
    __shared__ unsigned short Xs[TM * D_];
    __shared__ unsigned short Hs[TM * H_];
    __shared__ int   tks[TM];
    __shared__ float gs[TM];

    const int bi = blockIdx.x;
    const int e = bi & 7;
    const int t0 = (bi >> 3) * TM;
    const int n = counts[e];
    if (t0 >= n) return;
    const int tid = threadIdx.x;
    const int mact = min(TM, n - t0);
    const int wave = tid >> 6;
    const int lane = tid & 63;
    const int m = lane & 15;
    const int g = lane >> 4;
    char* XsC = (char*)Xs;
    char* HsC = (char*)Hs;

    if (tid < TM) {
        if (tid < mact) {
            tks[tid] = lists[e * NT_ + t0 + tid];
            gs[tid]  = gvals[e * NT_ + t0 + tid];
        } else { tks[tid] = 0; gs[tid] = 0.f; }
    }
    __syncthreads();

    for (int idx = tid; idx < TM * (D_ / 8); idx += 256) {
        const int mm = idx >> 6;
        const int c8 = idx & 63;
        union { unsigned short u[8]; uint4 v; } p;
        if (mm < mact) {
            const float4* xr = (const float4*)(x + (size_t)tks[mm] * D_);
            const float4 v0 = xr[c8 * 2], v1 = xr[c8 * 2 + 1];
            p.u[0]=f2bf(v0.x); p.u[1]=f2bf(v0.y); p.u[2]=f2bf(v0.z); p.u[3]=f2bf(v0.w);
            p.u[4]=f2bf(v1.x); p.u[5]=f2bf(v1.y); p.u[6]=f2bf(v1.z); p.u[7]=f2bf(v1.w);
        } else {
            p.v = make_uint4(0, 0, 0, 0);
        }
        const int off = mm * (D_ * 2) + c8 * 16;
        *(uint4*)(XsC + (off ^ ((mm & 7) << 4))) = p.v;
    }
    __syncthreads();

    const int nbase = wave * 256;
    f32x4 acc1[16];
#pragma unroll
    for (int f = 0; f < 16; ++f) acc1[f] = (f32x4){0.f, 0.f, 0.f, 0.f};

    for (int k0 = 0; k0 < D_; k0 += 32) {
        const int aoff = m * (D_ * 2) + k0 * 2 + g * 16;
        const short8v a = *(const short8v*)(XsC + (aoff ^ ((m & 7) << 4)));
#pragma unroll
        for (int f = 0; f < 16; ++f) {
            const unsigned short* bp = W1T + (((size_t)(e << 10) + nbase + f * 16 + m) << 9) + k0 + g * 8;
            const short8v b = *(const short8v*)bp;
            acc1[f] = __builtin_amdgcn_mfma_f32_16x16x32_bf16(a, b, acc1[f], 0, 0, 0);
        }
    }
#pragma unroll
    for (int f = 0; f < 16; ++f) {
        const int nn = nbase + f * 16 + m;
        const float bias = b1[(e << 10) + nn];
#pragma unroll
        for (int r = 0; r < 4; ++r) {
            const int mm = g * 4 + r;
            const unsigned short hv = f2bf(fmaxf(acc1[f][r] + bias, 0.f));
            const int off = mm * (H_ * 2) + nn * 2;
            *(unsigned short*)(HsC + (off ^ ((mm & 7) << 4))) = hv;
        }
    }
    __syncthreads();

    const int obase = wave * 128;
    f32x4 acc2[8];
#pragma unroll
    for (int f = 0; f < 8; ++f) acc2[f] = (f32x4){0.f, 0.f, 0.f, 0.f};

    for (int k0 = 0; k0 < H_; k0 += 32) {
        const int aoff = m * (H_ * 2) + k0 * 2 + g * 16;
        const short8v a = *(const short8v*)(HsC + (aoff ^ ((m & 7) << 4)));
#pragma unroll
        for (int f = 0; f < 8; ++f) {
            const unsigned short* bp = W2T + (((size_t)(e << 9) + obase + f * 16 + m) << 10) + k0 + g * 8;
            const short8v b = *(const short8v*)bp;
            acc2[f] = __builtin_amdgcn_mfma_f32_16x16x32_bf16(a, b, acc2[f], 0, 0, 0);
        }
    }
#pragma unroll
    for (int f = 0; f < 8; ++f) {
        const int o = obase + f * 16 + m;
        const float bias = b2[(e << 9) + o];
#pragma unroll
        for (int r = 0; r < 4; ++r) {
            const int mm = g * 4 + r;
            const float gv = gs[mm];
            if (gv != 0.f)
                atomicAdd(out + (size_t)tks[mm] * D_ + o, (acc2[f][r] + bias) * gv);
        }
    }
}

__global__ __launch_bounds__(256) void expert_fp32(
    const float* __restrict__ x,
    const float* __restrict__ W1, const float* __restrict__ b1,
    const float* __restrict__ W2, const float* __restrict__ b2,
    const int* __restrict__ counts, const int* __restrict__ lists,
    const float* __restrict__ gvals, float* __restrict__ out)
{
    __shared__ float Xs[TM][D_];
    __shared__ float Hs[TM][H_];
    __shared__ int   tks[TM];
    __shared__ float gs[TM];

    const int e  = blockIdx.y;
    const int n  = counts[e];
    const int t0 = blockIdx.x * TM;
    if (t0 >= n) return;
    const int tid  = threadIdx.x;
    const int mact = min(TM, n - t0);

    if (tid < TM) {
        if (tid < mact) {
            tks[tid] = lists[e * NT_ + t0 + tid];
            gs[tid]  = gvals[e * NT_ + t0 + tid];
        } else { tks[tid] = 0; gs[tid] = 0.f; }
    }
    __syncthreads();
    for (int idx = tid; idx < TM * (D_ / 4); idx += 256) {
        const int mm = idx >> 7, c = idx & 127;
        float4 v = make_float4(0.f, 0.f, 0.f, 0.f);
        if (mm < mact) v = ((const float4*)(x + (size_t)tks[mm] * D_))[c];
        ((float4*)&Xs[mm][0])[c] = v;
    }
    __syncthreads();
    const float* W1e = W1 + (size_t)e * D_ * H_;
    float acc[4][TM];
#pragma unroll
    for (int jj = 0; jj < 4; ++jj)
#pragma unroll
        for (int mm = 0; mm < TM; ++mm) acc[jj][mm] = 0.f;
    for (int d4 = 0; d4 < D_ / 4; ++d4) {
        float w[4][4];
#pragma unroll
        for (int dd = 0; dd < 4; ++dd) {
            const float* wp = W1e + (size_t)(d4 * 4 + dd) * H_ + tid;
#pragma unroll
            for (int jj = 0; jj < 4; ++jj) w[dd][jj] = wp[jj * 256];
        }
#pragma unroll
        for (int mm = 0; mm < TM; ++mm) {
            const float4 xv = ((const float4*)&Xs[mm][0])[d4];
            const float* xp = &xv.x;
#pragma unroll
            for (int dd = 0; dd < 4; ++dd)
#pragma unroll
                for (int jj = 0; jj < 4; ++jj)
                    acc[jj][mm] = fmaf(xp[dd], w[dd][jj], acc[jj][mm]);
        }
    }
#pragma unroll
    for (int jj = 0; jj < 4; ++jj) {
        const int j = jj * 256 + tid;
        const float bv = b1[e * H_ + j];
#pragma unroll
        for (int mm = 0; mm < TM; ++mm) Hs[mm][j] = fmaxf(acc[jj][mm] + bv, 0.f);
    }
    __syncthreads();
    const float* W2e = W2 + (size_t)e * H_ * D_;
    float acc2[2][TM];
#pragma unroll
    for (int oo = 0; oo < 2; ++oo)
#pragma unroll
        for (int mm = 0; mm < TM; ++mm) acc2[oo][mm] = 0.f;
    for (int j4 = 0; j4 < H_ / 4; ++j4) {
        float w[4][2];
#pragma unroll
        for (int dd = 0; dd < 4; ++dd) {
            const float* wp = W2e + (size_t)(j4 * 4 + dd) * D_ + tid;
#pragma unroll
            for (int oo = 0; oo < 2; ++oo) w[dd][oo] = wp[oo * 256];
        }
#pragma unroll
        for (int mm = 0; mm < TM; ++mm) {
            const float4 hv = ((const float4*)&Hs[mm][0])[j4];
            const float* hp = &hv.x;
#pragma unroll
            for (int dd = 0; dd < 4; ++dd)
#pragma unroll
                for (int oo = 0; oo < 2; ++oo)
                    acc2[oo][mm] = fmaf(hp[dd], w[dd][oo], acc2[oo][mm]);
        }
    }
#pragma unroll
    for (int oo = 0; oo < 2; ++oo) {
        const int o = oo * 256 + tid;
        const float bv = b2[e * D_ + o];
        for (int mm = 0; mm < mact; ++mm)
            atomicAdd(out + (size_t)tks[mm] * D_ + o, (acc2[oo][mm] + bv) * gs[mm]);
    }
}

// ======================= host launcher =======================

extern "C" void kernel_launch(void* const* d_in, const int* in_sizes, int n_in,
                              void* d_out, int out_size, void* d_ws, size_t ws_size,
                              hipStream_t stream)
{
    const float* x    = (const float*)d_in[0];
    const int*   mask = (const int*)d_in[1];
    const float* wg   = (const float*)d_in[2];
    const float* W1   = (const float*)d_in[3];
    const float* b1   = (const float*)d_in[4];
    const float* W2   = (const float*)d_in[5];
    const float* b2   = (const float*)d_in[6];
    float* out = (float*)d_out;

    char* ws = (char*)d_ws;
    int*   counts = (int*)ws;                       // 32 B
    int*   lists  = (int*)(ws + 256);               // 128 KB
    float* gvals  = (float*)(ws + 256 + 131072);    // 128 KB

    // Tier A layout
    uchar2* tokE = (uchar2*)(ws + 0x48000);                             // 8 KB
    float2* tokG = (float2*)(ws + 0x50000);                             // 32 KB
    unsigned short* xbf  = (unsigned short*)(ws + 0x60000);             // 4 MB
    unsigned short* W1Sa = (unsigned short*)(ws + 0x480000);            // 8 MB
    unsigned short* W2Sa = (unsigned short*)(ws + 0xC80000);            // 8 MB
    unsigned short* Hbuf = (unsigned short*)(ws + 0x1480000);           // 16.5 MB
    const size_t needA = 0x1480000 + (size_t)8448 * 1024 * 2;           // ~38.8 MB

    const size_t wt_bytes = (size_t)E_ * D_ * H_ * 2;
    const size_t needB = 524288 + 2 * wt_bytes;                         // ~17.3 MB

    if (ws_size >= needA) {
        prep_fused<<<5120, 256, 0, stream>>>(x, mask, wg, W1, W2,
                                             out, xbf, tokE, tokG, W1Sa, W2Sa);
        build_kernel<<<1, 256, 0, stream>>>(tokE, tokG, counts, lists, gvals);
        stage1_kernel<<<264 * 4, 256, 0, stream>>>(xbf, W1Sa, b1, counts, lists, Hbuf);
        stage2_kernel<<<264 * 2, 256, 0, stream>>>(Hbuf, W2Sa, b2, counts, lists, gvals, out);
    } else if (ws_size >= needB) {
        unsigned short* W1T = (unsigned short*)(ws + 524288);
        unsigned short* W2T = (unsigned short*)(ws + 524288 + wt_bytes);
        hipMemsetAsync(counts, 0, E_ * sizeof(int), stream);
        gating_kernel<<<NT_ / 4, 256, 0, stream>>>(x, mask, wg, counts, lists, gvals);
        init_out_kernel<<<(NT_ * D_) / 4 / 256, 256, 0, stream>>>(x, out);
        transpose_cvt<<<dim3(H_ / 64, D_ / 64, E_), 256, 0, stream>>>(W1, W1T, D_, H_);
        transpose_cvt<<<dim3(D_ / 64, H_ / 64, E_), 256, 0, stream>>>(W2, W2T, H_, D_);
        expert_mfma<<<(NT_ / TM) * E_, 256, 0, stream>>>(x, W1T, b1, W2T, b2,
                                                         counts, lists, gvals, out);
    } else {
        hipMemsetAsync(counts, 0, E_ * sizeof(int), stream);
        gating_kernel<<<NT_ / 4, 256, 0, stream>>>(x, mask, wg, counts, lists, gvals);
        init_out_kernel<<<(NT_ * D_) / 4 / 256, 256, 0, stream>>>(x, out);
        expert_fp32<<<dim3(NT_ / TM, E_), 256, 0, stream>>>(x, W1, b1, W2, b2,
                                                            counts, lists, gvals, out);
    }
}

// Round 7
// 116.749 us; speedup vs baseline: 1.0407x; 1.0407x over previous
//
#include <hip/hip_runtime.h>
#include <cmath>

#define B_ 8
#define S_ 512
#define D_ 512
#define H_ 1024
#define E_ 8
#define NT_ (B_*S_)   // 4096 tokens
#define TM 16         // tokens per tile (fallback path)
#define MAXTILE 40    // tiles per expert in stage grids (capacity 1280 tokens/expert)

typedef __attribute__((ext_vector_type(8))) short short8v;
typedef __attribute__((ext_vector_type(4))) float f32x4;

__device__ inline unsigned short f2bf(float f) {
    union { float f; unsigned u; } a; a.f = f;
    unsigned u = a.u;
    return (unsigned short)((u + 0x7FFF + ((u >> 16) & 1)) >> 16);  // RNE
}

// ======================= TIER A (main path) =======================

// ---- prep_fused ----
// blocks 0..1023   : out = x, xbf = bf16(x), per-token gating (no atomics)
// blocks 1024..2047: W1 repack, F-PAIRED: one wave -> chunks (2Fp,kidx),(2Fp+1,kidx)
// blocks 2048..3071: W2 repack, F-paired likewise.
// Pairing makes every global read a full 128B line (cols Fp*32..Fp*32+32).
__global__ __launch_bounds__(256) void prep_fused(
    const float* __restrict__ x, const int* __restrict__ mask,
    const float* __restrict__ wg,
    const float* __restrict__ W1, const float* __restrict__ W2,
    float* __restrict__ out, unsigned short* __restrict__ xbf,
    uchar2* __restrict__ tokE, float2* __restrict__ tokG,
    unsigned short* __restrict__ W1S, unsigned short* __restrict__ W2S)
{
    const int tid = threadIdx.x, wave = tid >> 6, lane = tid & 63;
    const int bid = blockIdx.x;

    if (bid < 1024) {
        // -------- x pass + gating: one wave per token --------
        const int t = bid * 4 + wave;
        const float4* xr = (const float4*)(x + ((size_t)t << 9));
        const float4 v0 = xr[lane];
        const float4 v1 = xr[lane + 64];
        float4* orow = (float4*)(out + ((size_t)t << 9));
        orow[lane] = v0; orow[lane + 64] = v1;
        union { unsigned short u[4]; uint2 w; } pa, pb;
        pa.u[0]=f2bf(v0.x); pa.u[1]=f2bf(v0.y); pa.u[2]=f2bf(v0.z); pa.u[3]=f2bf(v0.w);
        pb.u[0]=f2bf(v1.x); pb.u[1]=f2bf(v1.y); pb.u[2]=f2bf(v1.z); pb.u[3]=f2bf(v1.w);
        uint2* xrow = (uint2*)(xbf + ((size_t)t << 9));
        xrow[lane] = pa.w; xrow[lane + 64] = pb.w;

        float acc[E_];
#pragma unroll
        for (int e = 0; e < E_; ++e) acc[e] = 0.f;
        const int d0 = lane * 4;
#pragma unroll
        for (int dd = 0; dd < 4; ++dd) {
            const float xa = (&v0.x)[dd], xb = (&v1.x)[dd];
            const float4 wa0 = *(const float4*)(wg + (size_t)(d0 + dd) * 8);
            const float4 wa1 = *(const float4*)(wg + (size_t)(d0 + dd) * 8 + 4);
            const float4 wb0 = *(const float4*)(wg + (size_t)(256 + d0 + dd) * 8);
            const float4 wb1 = *(const float4*)(wg + (size_t)(256 + d0 + dd) * 8 + 4);
            acc[0] += xa * wa0.x + xb * wb0.x;
            acc[1] += xa * wa0.y + xb * wb0.y;
            acc[2] += xa * wa0.z + xb * wb0.z;
            acc[3] += xa * wa0.w + xb * wb0.w;
            acc[4] += xa * wa1.x + xb * wb1.x;
            acc[5] += xa * wa1.y + xb * wb1.y;
            acc[6] += xa * wa1.z + xb * wb1.z;
            acc[7] += xa * wa1.w + xb * wb1.w;
        }
#pragma unroll
        for (int e = 0; e < E_; ++e) {
            float v = acc[e];
#pragma unroll
            for (int off = 32; off > 0; off >>= 1) v += __shfl_xor(v, off, 64);
            acc[e] = v;
        }
        if (lane == 0) {
            if (mask[t] != 0) {
                int i0 = 0; float v0m = acc[0];
#pragma unroll
                for (int e = 1; e < E_; ++e) if (acc[e] > v0m) { v0m = acc[e]; i0 = e; }
                int i1 = -1; float v1m = -INFINITY;
#pragma unroll
                for (int e = 0; e < E_; ++e) if (e != i0 && acc[e] > v1m) { v1m = acc[e]; i1 = e; }
                const float ex = __expf(v1m - v0m);
                const float denom = 1.f + ex;
                tokE[t] = make_uchar2((unsigned char)i0, (unsigned char)i1);
                tokG[t] = make_float2(1.f / denom, ex / denom);
            } else {
                tokE[t] = make_uchar2(255, 255);
            }
        }
        return;
    }

    // -------- F-paired direct repack: one wave -> two 1KB chunks --------
    const int isW2 = (bid >= 2048);
    const int p = ((bid - (isW2 ? 2048 : 1024)) << 2) | wave;   // 0..4095
    const int e = p >> 9, rem2 = p & 511;
    const int g = lane >> 4, m = lane & 15;
    const float* base; unsigned short* dstB; int stride, K32, Fp, kidx;
    if (!isW2) {
        Fp = rem2 >> 4; kidx = rem2 & 15;   // Fp 0..31, kidx 0..15
        stride = H_; K32 = 16; base = W1; dstB = W1S;
    } else {
        Fp = rem2 >> 5; kidx = rem2 & 31;   // Fp 0..15, kidx 0..31
        stride = D_; K32 = 32; base = W2; dstB = W2S;
    }
    const int k = kidx * 32 + g * 8;
    const float* src = base + ((size_t)e << 19) + (size_t)k * stride + Fp * 32 + m;
    unsigned short* dst0 = dstB + ((size_t)e << 19)
                         + ((size_t)(2 * Fp * K32 + kidx) << 9) + lane * 8;
    unsigned short* dst1 = dst0 + ((size_t)K32 << 9);
    float v0[8], v1[8];
#pragma unroll
    for (int j = 0; j < 8; ++j) {
        v0[j] = src[(size_t)j * stride];
        v1[j] = src[(size_t)j * stride + 16];
    }
    union { unsigned short u[8]; uint4 q; } p0, p1;
#pragma unroll
    for (int j = 0; j < 8; ++j) { p0.u[j] = f2bf(v0[j]); p1.u[j] = f2bf(v1[j]); }
    *(uint4*)dst0 = p0.q;
    *(uint4*)dst1 = p1.q;
}

// ---- build_kernel: single block, deterministic counting sort (no atomics) ----
__global__ __launch_bounds__(256) void build_kernel(
    const uchar2* __restrict__ tokE, const float2* __restrict__ tokG,
    int* __restrict__ counts, int* __restrict__ lists, float* __restrict__ gvals)
{
    __shared__ int waveTot[4][E_];
    __shared__ int waveBase[4][E_];
    const int tid = threadIdx.x;
    const int lane = tid & 63, wave = tid >> 6;
    int h[E_];
#pragma unroll
    for (int e = 0; e < E_; ++e) h[e] = 0;
#pragma unroll
    for (int j = 0; j < 16; ++j) {
        const uchar2 ee = tokE[tid * 16 + j];
#pragma unroll
        for (int e = 0; e < E_; ++e) h[e] += (ee.x == e) + (ee.y == e);
    }
    int pre[E_];
#pragma unroll
    for (int e = 0; e < E_; ++e) {
        int v = h[e];
#pragma unroll
        for (int off = 1; off < 64; off <<= 1) {
            const int o = __shfl_up(v, off, 64);
            if (lane >= off) v += o;
        }
        pre[e] = v - h[e];
        if (lane == 63) waveTot[wave][e] = v;
    }
    __syncthreads();
    if (tid < E_) {
        int s = 0;
#pragma unroll
        for (int w = 0; w < 4; ++w) { const int v = waveTot[w][tid]; waveBase[w][tid] = s; s += v; }
        counts[tid] = s;
    }
    __syncthreads();
    int base[E_], cnt[E_];
#pragma unroll
    for (int e = 0; e < E_; ++e) { base[e] = waveBase[wave][e] + pre[e]; cnt[e] = 0; }
#pragma unroll
    for (int j = 0; j < 16; ++j) {
        const int t = tid * 16 + j;
        const uchar2 ee = tokE[t];
        if (ee.x == 255) continue;
        const float2 gg = tokG[t];
#pragma unroll
        for (int e = 0; e < E_; ++e) {
            if (ee.x == e) { const int s = base[e] + cnt[e]; lists[e * NT_ + s] = t; gvals[e * NT_ + s] = gg.x; cnt[e]++; }
            if (ee.y == e) { const int s = base[e] + cnt[e]; lists[e * NT_ + s] = t; gvals[e * NT_ + s] = gg.y; cnt[e]++; }
        }
    }
}

// ---- stage1: H[slot][h] = relu(Xbf[tok] @ W1 + b1), streaming MFMA ----
// bid = (ti*4+nb)*8 + e  -> expert e pinned to XCD (bid%8); grid = MAXTILE*4*8
__global__ __launch_bounds__(256) void stage1_kernel(
    const unsigned short* __restrict__ xbf,
    const unsigned short* __restrict__ W1S, const float* __restrict__ b1,
    const int* __restrict__ counts, const int* __restrict__ lists,
    unsigned short* __restrict__ Hbuf)
{
    const int bid = blockIdx.x;
    const int e  = bid & 7;
    const int nb = (bid >> 3) & 3;
    const int ti = bid >> 5;
    const int n_e = counts[e];
    const int t0 = ti << 5;
    if (t0 >= n_e) return;
    int off = 0;
#pragma unroll
    for (int i = 0; i < E_; ++i) if (i < e) off += counts[i];
    const int mact = min(32, n_e - t0);
    __shared__ int tks[32];
    const int tid = threadIdx.x;
    if (tid < 32) tks[tid] = lists[e * NT_ + t0 + min(tid, mact - 1)];
    __syncthreads();

    const int wave = tid >> 6, lane = tid & 63, m = lane & 15, g = lane >> 4;
    const int colbase = nb * 256 + wave * 64;

    const unsigned short* a0p = xbf + ((size_t)tks[m] << 9) + (g << 3);
    const unsigned short* a1p = xbf + ((size_t)tks[16 + m] << 9) + (g << 3);
    const unsigned short* Bb = W1S + ((size_t)e << 19)
                             + ((size_t)(nb * 16 + wave * 4) << 13) + (lane << 3);

    f32x4 acc[2][4];
#pragma unroll
    for (int i = 0; i < 2; ++i)
#pragma unroll
        for (int f = 0; f < 4; ++f) acc[i][f] = (f32x4){0.f, 0.f, 0.f, 0.f};

#pragma unroll 2
    for (int kk = 0; kk < 16; ++kk) {
        const short8v a0 = *(const short8v*)(a0p + (kk << 5));
        const short8v a1 = *(const short8v*)(a1p + (kk << 5));
        const short8v b0  = *(const short8v*)(Bb + (kk << 9));
        const short8v b1v = *(const short8v*)(Bb + (1 << 13) + (kk << 9));
        const short8v b2v = *(const short8v*)(Bb + (2 << 13) + (kk << 9));
        const short8v b3  = *(const short8v*)(Bb + (3 << 13) + (kk << 9));
        acc[0][0] = __builtin_amdgcn_mfma_f32_16x16x32_bf16(a0, b0,  acc[0][0], 0, 0, 0);
        acc[1][0] = __builtin_amdgcn_mfma_f32_16x16x32_bf16(a1, b0,  acc[1][0], 0, 0, 0);
        acc[0][1] = __builtin_amdgcn_mfma_f32_16x16x32_bf16(a0, b1v, acc[0][1], 0, 0, 0);
        acc[1][1] = __builtin_amdgcn_mfma_f32_16x16x32_bf16(a1, b1v, acc[1][1], 0, 0, 0);
        acc[0][2] = __builtin_amdgcn_mfma_f32_16x16x32_bf16(a0, b2v, acc[0][2], 0, 0, 0);
        acc[1][2] = __builtin_amdgcn_mfma_f32_16x16x32_bf16(a1, b2v, acc[1][2], 0, 0, 0);
        acc[0][3] = __builtin_amdgcn_mfma_f32_16x16x32_bf16(a0, b3,  acc[0][3], 0, 0, 0);
        acc[1][3] = __builtin_amdgcn_mfma_f32_16x16x32_bf16(a1, b3,  acc[1][3], 0, 0, 0);
    }

#pragma unroll
    for (int f = 0; f < 4; ++f) {
        const int col = colbase + f * 16 + m;
        const float bias = b1[(e << 10) + col];
#pragma unroll
        for (int i = 0; i < 2; ++i)
#pragma unroll
            for (int r = 0; r < 4; ++r) {
                const int row = i * 16 + g * 4 + r;
                if (row < mact)
                    Hbuf[((size_t)(off + t0 + row) << 10) + col] =
                        f2bf(fmaxf(acc[i][f][r] + bias, 0.f));
            }
    }
}

// ---- stage2: out[tok] += gate * (H[slot] @ W2 + b2), streaming MFMA ----
// bid = (ti*2+nb)*8 + e; grid = MAXTILE*2*8
__global__ __launch_bounds__(256) void stage2_kernel(
    const unsigned short* __restrict__ Hbuf,
    const unsigned short* __restrict__ W2S, const float* __restrict__ b2,
    const int* __restrict__ counts, const int* __restrict__ lists,
    const float* __restrict__ gvals, float* __restrict__ out)
{
    const int bid = blockIdx.x;
    const int e  = bid & 7;
    const int nb = (bid >> 3) & 1;
    const int ti = bid >> 4;
    const int n_e = counts[e];
    const int t0 = ti << 5;
    if (t0 >= n_e) return;
    int off = 0;
#pragma unroll
    for (int i = 0; i < E_; ++i) if (i < e) off += counts[i];
    const int mact = min(32, n_e - t0);
    __shared__ int tks[32];
    __shared__ float gsh[32];
    const int tid = threadIdx.x;
    if (tid < 32) {
        const int idx = min(tid, mact - 1);
        tks[tid] = lists[e * NT_ + t0 + idx];
        gsh[tid] = gvals[e * NT_ + t0 + idx];
    }
    __syncthreads();

    const int wave = tid >> 6, lane = tid & 63, m = lane & 15, g = lane >> 4;
    const int colbase = nb * 256 + wave * 64;

    const unsigned short* a0p = Hbuf + ((size_t)(off + t0 + m) << 10) + (g << 3);
    const unsigned short* a1p = Hbuf + ((size_t)(off + t0 + 16 + m) << 10) + (g << 3);
    const unsigned short* Bb = W2S + ((size_t)e << 19)
                             + ((size_t)(nb * 16 + wave * 4) << 14) + (lane << 3);

    f32x4 acc[2][4];
#pragma unroll
    for (int i = 0; i < 2; ++i)
#pragma unroll
        for (int f = 0; f < 4; ++f) acc[i][f] = (f32x4){0.f, 0.f, 0.f, 0.f};

#pragma unroll 2
    for (int kk = 0; kk < 32; ++kk) {
        const short8v a0 = *(const short8v*)(a0p + (kk << 5));
        const short8v a1 = *(const short8v*)(a1p + (kk << 5));
        const short8v b0  = *(const short8v*)(Bb + (kk << 9));
        const short8v b1v = *(const short8v*)(Bb + (1 << 14) + (kk << 9));
        const short8v b2v = *(const short8v*)(Bb + (2 << 14) + (kk << 9));
        const short8v b3  = *(const short8v*)(Bb + (3 << 14) + (kk << 9));
        acc[0][0] = __builtin_amdgcn_mfma_f32_16x16x32_bf16(a0, b0,  acc[0][0], 0, 0, 0);
        acc[1][0] = __builtin_amdgcn_mfma_f32_16x16x32_bf16(a1, b0,  acc[1][0], 0, 0, 0);
        acc[0][1] = __builtin_amdgcn_mfma_f32_16x16x32_bf16(a0, b1v, acc[0][1], 0, 0, 0);
        acc[1][1] = __builtin_amdgcn_mfma_f32_16x16x32_bf16(a1, b1v, acc[1][1], 0, 0, 0);
        acc[0][2] = __builtin_amdgcn_mfma_f32_16x16x32_bf16(a0, b2v, acc[0][2], 0, 0, 0);
        acc[1][2] = __builtin_amdgcn_mfma_f32_16x16x32_bf16(a1, b2v, acc[1][2], 0, 0, 0);
        acc[0][3] = __builtin_amdgcn_mfma_f32_16x16x32_bf16(a0, b3,  acc[0][3], 0, 0, 0);
        acc[1][3] = __builtin_amdgcn_mfma_f32_16x16x32_bf16(a1, b3,  acc[1][3], 0, 0, 0);
    }

#pragma unroll
    for (int f = 0; f < 4; ++f) {
        const int col = colbase + f * 16 + m;
        const float bias = b2[(e << 9) + col];
#pragma unroll
        for (int i = 0; i < 2; ++i)
#pragma unroll
            for (int r = 0; r < 4; ++r) {
                const int row = i * 16 + g * 4 + r;
                if (row < mact)
                    atomicAdd(out + ((size_t)tks[row] << 9) + col,
                              (acc[i][f][r] + bias) * gsh[row]);
            }
    }
}

// ======================= TIER B/C fallbacks =======================

__global__ __launch_bounds__(256) void gating_kernel(
    const float* __restrict__ x, const int* __restrict__ mask,
    const float* __restrict__ wg, int* __restrict__ counts,
    int* __restrict__ lists, float* __restrict__ gvals)
{
    const int wave = threadIdx.x >> 6;
    const int lane = threadIdx.x & 63;
    const int t = blockIdx.x * 4 + wave;
    const float* xr = x + (size_t)t * D_;
    float acc[E_];
#pragma unroll
    for (int e = 0; e < E_; ++e) acc[e] = 0.f;
    for (int d = lane; d < D_; d += 64) {
        const float xv = xr[d];
        const float* wr = wg + (size_t)d * E_;
#pragma unroll
        for (int e = 0; e < E_; ++e) acc[e] += xv * wr[e];
    }
#pragma unroll
    for (int e = 0; e < E_; ++e) {
        float v = acc[e];
#pragma unroll
        for (int off = 32; off > 0; off >>= 1) v += __shfl_down(v, off, 64);
        acc[e] = v;
    }
    if (lane == 0 && mask[t] != 0) {
        int i0 = 0; float v0 = acc[0];
#pragma unroll
        for (int e = 1; e < E_; ++e) if (acc[e] > v0) { v0 = acc[e]; i0 = e; }
        int i1 = -1; float v1 = -INFINITY;
#pragma unroll
        for (int e = 0; e < E_; ++e) if (e != i0 && acc[e] > v1) { v1 = acc[e]; i1 = e; }
        const float ex = __expf(v1 - v0);
        const float denom = 1.f + ex;
        const int p0 = atomicAdd(&counts[i0], 1);
        lists[i0 * NT_ + p0] = t; gvals[i0 * NT_ + p0] = 1.f / denom;
        const int p1 = atomicAdd(&counts[i1], 1);
        lists[i1 * NT_ + p1] = t; gvals[i1 * NT_ + p1] = ex / denom;
    }
}

__global__ __launch_bounds__(256) void init_out_kernel(
    const float* __restrict__ x, float* __restrict__ out)
{
    const size_t i = (size_t)blockIdx.x * blockDim.x + threadIdx.x;
    ((float4*)out)[i] = ((const float4*)x)[i];
}

__global__ __launch_bounds__(256) void transpose_cvt(
    const float* __restrict__ src, unsigned short* __restrict__ dst, int R, int C)
{
    __shared__ unsigned short t[64][72];
    const float* s = src + (size_t)blockIdx.z * R * C;
    unsigned short* d = dst + (size_t)blockIdx.z * R * C;
    const int r0 = blockIdx.y * 64, c0 = blockIdx.x * 64;
    const int tc = threadIdx.x & 63;
    const int tr = threadIdx.x >> 6;
#pragma unroll
    for (int i = 0; i < 16; ++i) {
        const int r = tr + i * 4;
        t[r][tc] = f2bf(s[(size_t)(r0 + r) * C + c0 + tc]);
    }
    __syncthreads();
    const int c = threadIdx.x >> 2;
    const int ch = threadIdx.x & 3;
#pragma unroll
    for (int half = 0; half < 2; ++half) {
        union { unsigned short u[8]; uint4 v; } p;
#pragma unroll
        for (int k = 0; k < 8; ++k) p.u[k] = t[ch * 16 + half * 8 + k][c];
        *(uint4*)(d + (size_t)(c0 + c) * R + r0 + ch * 16 + half * 8) = p.v;
    }
}

__global__ __launch_bounds__(256) void expert_mfma(
    const float* __restrict__ x,
    const unsigned short* __restrict__ W1T, const float* __restrict__ b1,
    const unsigned short* __restrict__ W2T, const float* __restrict__ b2,
    const int* __restrict__ counts, const int* __restrict__ lists,
    const float* __restrict__ gvals, float* __restrict__ out)
{
    __shared__ unsigned short Xs[TM * D_];
    __shared__ unsigned short Hs[TM * H_];
    __shared__ int   tks[TM];
    __shared__ float gs[TM];

    const int bi = blockIdx.x;
    const int e = bi & 7;
    const int t0 = (bi >> 3) * TM;
    const int n = counts[e];
    if (t0 >= n) return;
    const int tid = threadIdx.x;
    const int mact = min(TM, n - t0);
    const int wave = tid >> 6;
    const int lane = tid & 63;
    const int m = lane & 15;
    const int g = lane >> 4;
    char* XsC = (char*)Xs;
    char* HsC = (char*)Hs;

    if (tid < TM) {
        if (tid < mact) {
            tks[tid] = lists[e * NT_ + t0 + tid];
            gs[tid]  = gvals[e * NT_ + t0 + tid];
        } else { tks[tid] = 0; gs[tid] = 0.f; }
    }
    __syncthreads();

    for (int idx = tid; idx < TM * (D_ / 8); idx += 256) {
        const int mm = idx >> 6;
        const int c8 = idx & 63;
        union { unsigned short u[8]; uint4 v; } p;
        if (mm < mact) {
            const float4* xr = (const float4*)(x + (size_t)tks[mm] * D_);
            const float4 v0 = xr[c8 * 2], v1 = xr[c8 * 2 + 1];
            p.u[0]=f2bf(v0.x); p.u[1]=f2bf(v0.y); p.u[2]=f2bf(v0.z); p.u[3]=f2bf(v0.w);
            p.u[4]=f2bf(v1.x); p.u[5]=f2bf(v1.y); p.u[6]=f2bf(v1.z); p.u[7]=f2bf(v1.w);
        } else {
            p.v = make_uint4(0, 0, 0, 0);
        }
        const int off = mm * (D_ * 2) + c8 * 16;
        *(uint4*)(XsC + (off ^ ((mm & 7) << 4))) = p.v;
    }
    __syncthreads();

    const int nbase = wave * 256;
    f32x4 acc1[16];
#pragma unroll
    for (int f = 0; f < 16; ++f) acc1[f] = (f32x4){0.f, 0.f, 0.f, 0.f};

    for (int k0 = 0; k0 < D_; k0 += 32) {
        const int aoff = m * (D_ * 2) + k0 * 2 + g * 16;
        const short8v a = *(const short8v*)(XsC + (aoff ^ ((m & 7) << 4)));
#pragma unroll
        for (int f = 0; f < 16; ++f) {
            const unsigned short* bp = W1T + (((size_t)(e << 10) + nbase + f * 16 + m) << 9) + k0 + g * 8;
            const short8v b = *(const short8v*)bp;
            acc1[f] = __builtin_amdgcn_mfma_f32_16x16x32_bf16(a, b, acc1[f], 0, 0, 0);
        }
    }
#pragma unroll
    for (int f = 0; f < 16; ++f) {
        const int nn = nbase + f * 16 + m;
        const float bias = b1[(e << 10) + nn];
#pragma unroll
        for (int r = 0; r < 4; ++r) {
            const int mm = g * 4 + r;
            const unsigned short hv = f2bf(fmaxf(acc1[f][r] + bias, 0.f));
            const int off = mm * (H_ * 2) + nn * 2;
            *(unsigned short*)(HsC + (off ^ ((mm & 7) << 4))) = hv;
        }
    }
    __syncthreads();

    const int obase = wave * 128;
    f32x4 acc2[8];
#pragma unroll
    for (int f = 0; f < 8; ++f) acc2[f] = (f32x4){0.f, 0.f, 0.f, 0.f};

    for (int k0 = 0; k0 < H_; k0 += 32) {
        const int aoff = m * (H_ * 2) + k0 * 2 + g * 16;
        const short8v a = *(const short8v*)(HsC + (aoff ^ ((m & 7) << 4)));
#pragma unroll
        for (int f = 0; f < 8; ++f) {
            const unsigned short* bp = W2T + (((size_t)(e << 9) + obase + f * 16 + m) << 10) + k0 + g * 8;
            const short8v b = *(const short8v*)bp;
            acc2[f] = __builtin_amdgcn_mfma_f32_16x16x32_bf16(a, b, acc2[f], 0, 0, 0);
        }
    }
#pragma unroll
    for (int f = 0; f < 8; ++f) {
        const int o = obase + f * 16 + m;
        const float bias = b2[(e << 9) + o];
#pragma unroll
        for (int r = 0; r < 4; ++r) {
            const int mm = g * 4 + r;
            const float gv = gs[mm];
            if (gv != 0.f)
                atomicAdd(out + (size_t)tks[mm] * D_ + o, (acc2[f][r] + bias) * gv);
        }
    }
}

__global__ __launch_bounds__(256) void expert_fp32(
    const float* __restrict__ x,
    const float* __restrict__ W1, const float* __restrict__ b1,
    const float* __restrict__ W2, const float* __restrict__ b2,
    const int* __restrict__ counts, const int* __restrict__ lists,
    const float* __restrict__ gvals, float* __restrict__ out)
{
    __shared__ float Xs[TM][D_];
    __shared__ float Hs[TM][H_];
    __shared__ int   tks[TM];
    __shared__ float gs[TM];

    const int e  = blockIdx.y;
    const int n  = counts[e];
    const int t0 = blockIdx.x * TM;
    if (t0 >= n) return;
    const int tid  = threadIdx.x;
    const int mact = min(TM, n - t0);

    if (tid < TM) {
        if (tid < mact) {
            tks[tid] = lists[e * NT_ + t0 + tid];
            gs[tid]  = gvals[e * NT_ + t0 + tid];
        } else { tks[tid] = 0; gs[tid] = 0.f; }
    }
    __syncthreads();
    for (int idx = tid; idx < TM * (D_ / 4); idx += 256) {
        const int mm = idx >> 7, c = idx & 127;
        float4 v = make_float4(0.f, 0.f, 0.f, 0.f);
        if (mm < mact) v = ((const float4*)(x + (size_t)tks[mm] * D_))[c];
        ((float4*)&Xs[mm][0])[c] = v;
    }
    __syncthreads();
    const float* W1e = W1 + (size_t)e * D_ * H_;
    float acc[4][TM];
#pragma unroll
    for (int jj = 0; jj < 4; ++jj)
#pragma unroll
        for (int mm = 0; mm < TM; ++mm) acc[jj][mm] = 0.f;
    for (int d4 = 0; d4 < D_ / 4; ++d4) {
        float w[4][4];
#pragma unroll
        for (int dd = 0; dd < 4; ++dd) {
            const float* wp = W1e + (size_t)(d4 * 4 + dd) * H_ + tid;
#pragma unroll
            for (int jj = 0; jj < 4; ++jj) w[dd][jj] = wp[jj * 256];
        }
#pragma unroll
        for (int mm = 0; mm < TM; ++mm) {
            const float4 xv = ((const float4*)&Xs[mm][0])[d4];
            const float* xp = &xv.x;
#pragma unroll
            for (int dd = 0; dd < 4; ++dd)
#pragma unroll
                for (int jj = 0; jj < 4; ++jj)
                    acc[jj][mm] = fmaf(xp[dd], w[dd][jj], acc[jj][mm]);
        }
    }
#pragma unroll
    for (int jj = 0; jj < 4; ++jj) {
        const int j = jj * 256 + tid;
        const float bv = b1[e * H_ + j];
#pragma unroll
        for (int mm = 0; mm < TM; ++mm) Hs[mm][j] = fmaxf(acc[jj][mm] + bv, 0.f);
    }
    __syncthreads();
    const float* W2e = W2 + (size_t)e * H_ * D_;
    float acc2[2][TM];
#pragma unroll
    for (int oo = 0; oo < 2; ++oo)
#pragma unroll
        for (int mm = 0; mm < TM; ++mm) acc2[oo][mm] = 0.f;
    for (int j4 = 0; j4 < H_ / 4; ++j4) {
        float w[4][2];
#pragma unroll
        for (int dd = 0; dd < 4; ++dd) {
            const float* wp = W2e + (size_t)(j4 * 4 + dd) * D_ + tid;
#pragma unroll
            for (int oo = 0; oo < 2; ++oo) w[dd][oo] = wp[oo * 256];
        }
#pragma unroll
        for (int mm = 0; mm < TM; ++mm) {
            const float4 hv = ((const float4*)&Hs[mm][0])[j4];
            const float* hp = &hv.x;
#pragma unroll
            for (int dd = 0; dd < 4; ++dd)
#pragma unroll
                for (int oo = 0; oo < 2; ++oo)
                    acc2[oo][mm] = fmaf(hp[dd], w[dd][oo], acc2[oo][mm]);
        }
    }
#pragma unroll
    for (int oo = 0; oo < 2; ++oo) {
        const int o = oo * 256 + tid;
        const float bv = b2[e * D_ + o];
        for (int mm = 0; mm < mact; ++mm)
            atomicAdd(out + (size_t)tks[mm] * D_ + o, (acc2[oo][mm] + bv) * gs[mm]);
    }
}

// ======================= host launcher =======================

extern "C" void kernel_launch(void* const* d_in, const int* in_sizes, int n_in,
                              void* d_out, int out_size, void* d_ws, size_t ws_size,
                              hipStream_t stream)
{
    const float* x    = (const float*)d_in[0];
    const int*   mask = (const int*)d_in[1];
    const float* wg   = (const float*)d_in[2];
    const float* W1   = (const float*)d_in[3];
    const float* b1   = (const float*)d_in[4];
    const float* W2   = (const float*)d_in[5];
    const float* b2   = (const float*)d_in[6];
    float* out = (float*)d_out;

    char* ws = (char*)d_ws;
    int*   counts = (int*)ws;                       // 32 B
    int*   lists  = (int*)(ws + 256);               // 128 KB
    float* gvals  = (float*)(ws + 256 + 131072);    // 128 KB

    // Tier A layout
    uchar2* tokE = (uchar2*)(ws + 0x48000);                             // 8 KB
    float2* tokG = (float2*)(ws + 0x50000);                             // 32 KB
    unsigned short* xbf  = (unsigned short*)(ws + 0x60000);             // 4 MB
    unsigned short* W1Sa = (unsigned short*)(ws + 0x480000);            // 8 MB
    unsigned short* W2Sa = (unsigned short*)(ws + 0xC80000);            // 8 MB
    unsigned short* Hbuf = (unsigned short*)(ws + 0x1480000);           // 16.5 MB
    const size_t needA = 0x1480000 + (size_t)8448 * 1024 * 2;           // ~38.8 MB

    const size_t wt_bytes = (size_t)E_ * D_ * H_ * 2;
    const size_t needB = 524288 + 2 * wt_bytes;                         // ~17.3 MB

    if (ws_size >= needA) {
        prep_fused<<<3072, 256, 0, stream>>>(x, mask, wg, W1, W2,
                                             out, xbf, tokE, tokG, W1Sa, W2Sa);
        build_kernel<<<1, 256, 0, stream>>>(tokE, tokG, counts, lists, gvals);
        stage1_kernel<<<MAXTILE * 4 * 8, 256, 0, stream>>>(xbf, W1Sa, b1, counts, lists, Hbuf);
        stage2_kernel<<<MAXTILE * 2 * 8, 256, 0, stream>>>(Hbuf, W2Sa, b2, counts, lists, gvals, out);
    } else if (ws_size >= needB) {
        unsigned short* W1T = (unsigned short*)(ws + 524288);
        unsigned short* W2T = (unsigned short*)(ws + 524288 + wt_bytes);
        hipMemsetAsync(counts, 0, E_ * sizeof(int), stream);
        gating_kernel<<<NT_ / 4, 256, 0, stream>>>(x, mask, wg, counts, lists, gvals);
        init_out_kernel<<<(NT_ * D_) / 4 / 256, 256, 0, stream>>>(x, out);
        transpose_cvt<<<dim3(H_ / 64, D_ / 64, E_), 256, 0, stream>>>(W1, W1T, D_, H_);
        transpose_cvt<<<dim3(D_ / 64, H_ / 64, E_), 256, 0, stream>>>(W2, W2T, H_, D_);
        expert_mfma<<<(NT_ / TM) * E_, 256, 0, stream>>>(x, W1T, b1, W2T, b2,
                                                         counts, lists, gvals, out);
    } else {
        hipMemsetAsync(counts, 0, E_ * sizeof(int), stream);
        gating_kernel<<<NT_ / 4, 256, 0, stream>>>(x, mask, wg, counts, lists, gvals);
        init_out_kernel<<<(NT_ * D_) / 4 / 256, 256, 0, stream>>>(x, out);
        expert_fp32<<<dim3(NT_ / TM, E_), 256, 0, stream>>>(x, W1, b1, W2, b2,
                                                            counts, lists, gvals, out);
    }
}

// Round 9
// 87.977 us; speedup vs baseline: 1.3811x; 1.3270x over previous
//
#include <hip/hip_runtime.h>
#include <cmath>

#define B_ 8
#define S_ 512
#define D_ 512
#define H_ 1024
#define E_ 8
#define NT_ (B_*S_)   // 4096 tokens
#define TM 16         // tokens per tile (fallback path)
#define MAXTILE 40    // tiles per expert in stage grids (capacity 1280 tokens/expert)

typedef __attribute__((ext_vector_type(8))) short short8v;
typedef __attribute__((ext_vector_type(4))) float f32x4;

__device__ inline unsigned short f2bf(float f) {
    union { float f; unsigned u; } a; a.f = f;
    unsigned u = a.u;
    return (unsigned short)((u + 0x7FFF + ((u >> 16) & 1)) >> 16);  // RNE
}

// ======================= TIER A (main path) =======================

// ---- prep_fused ----
// blocks 0..1023   : out = x, xbf = bf16(x), per-token gating (no atomics)
// blocks 1024..2047: W1 repack, F-PAIRED; 2048..3071: W2 repack.
__global__ __launch_bounds__(256) void prep_fused(
    const float* __restrict__ x, const int* __restrict__ mask,
    const float* __restrict__ wg,
    const float* __restrict__ W1, const float* __restrict__ W2,
    float* __restrict__ out, unsigned short* __restrict__ xbf,
    uchar2* __restrict__ tokE, float2* __restrict__ tokG,
    unsigned short* __restrict__ W1S, unsigned short* __restrict__ W2S)
{
    const int tid = threadIdx.x, wave = tid >> 6, lane = tid & 63;
    const int bid = blockIdx.x;

    if (bid < 1024) {
        // -------- x pass + gating: one wave per token --------
        const int t = bid * 4 + wave;
        const float4* xr = (const float4*)(x + ((size_t)t << 9));
        const float4 v0 = xr[lane];
        const float4 v1 = xr[lane + 64];
        float4* orow = (float4*)(out + ((size_t)t << 9));
        orow[lane] = v0; orow[lane + 64] = v1;
        union { unsigned short u[4]; uint2 w; } pa, pb;
        pa.u[0]=f2bf(v0.x); pa.u[1]=f2bf(v0.y); pa.u[2]=f2bf(v0.z); pa.u[3]=f2bf(v0.w);
        pb.u[0]=f2bf(v1.x); pb.u[1]=f2bf(v1.y); pb.u[2]=f2bf(v1.z); pb.u[3]=f2bf(v1.w);
        uint2* xrow = (uint2*)(xbf + ((size_t)t << 9));
        xrow[lane] = pa.w; xrow[lane + 64] = pb.w;

        float acc[E_];
#pragma unroll
        for (int e = 0; e < E_; ++e) acc[e] = 0.f;
        const int d0 = lane * 4;
#pragma unroll
        for (int dd = 0; dd < 4; ++dd) {
            const float xa = (&v0.x)[dd], xb = (&v1.x)[dd];
            const float4 wa0 = *(const float4*)(wg + (size_t)(d0 + dd) * 8);
            const float4 wa1 = *(const float4*)(wg + (size_t)(d0 + dd) * 8 + 4);
            const float4 wb0 = *(const float4*)(wg + (size_t)(256 + d0 + dd) * 8);
            const float4 wb1 = *(const float4*)(wg + (size_t)(256 + d0 + dd) * 8 + 4);
            acc[0] += xa * wa0.x + xb * wb0.x;
            acc[1] += xa * wa0.y + xb * wb0.y;
            acc[2] += xa * wa0.z + xb * wb0.z;
            acc[3] += xa * wa0.w + xb * wb0.w;
            acc[4] += xa * wa1.x + xb * wb1.x;
            acc[5] += xa * wa1.y + xb * wb1.y;
            acc[6] += xa * wa1.z + xb * wb1.z;
            acc[7] += xa * wa1.w + xb * wb1.w;
        }
#pragma unroll
        for (int e = 0; e < E_; ++e) {
            float v = acc[e];
#pragma unroll
            for (int off = 32; off > 0; off >>= 1) v += __shfl_xor(v, off, 64);
            acc[e] = v;
        }
        if (lane == 0) {
            if (mask[t] != 0) {
                int i0 = 0; float v0m = acc[0];
#pragma unroll
                for (int e = 1; e < E_; ++e) if (acc[e] > v0m) { v0m = acc[e]; i0 = e; }
                int i1 = -1; float v1m = -INFINITY;
#pragma unroll
                for (int e = 0; e < E_; ++e) if (e != i0 && acc[e] > v1m) { v1m = acc[e]; i1 = e; }
                const float ex = __expf(v1m - v0m);
                const float denom = 1.f + ex;
                tokE[t] = make_uchar2((unsigned char)i0, (unsigned char)i1);
                tokG[t] = make_float2(1.f / denom, ex / denom);
            } else {
                tokE[t] = make_uchar2(255, 255);
            }
        }
        return;
    }

    // -------- F-paired direct repack: one wave -> two 1KB chunks --------
    const int isW2 = (bid >= 2048);
    const int p = ((bid - (isW2 ? 2048 : 1024)) << 2) | wave;   // 0..4095
    const int e = p >> 9, rem2 = p & 511;
    const int g = lane >> 4, m = lane & 15;
    const float* base; unsigned short* dstB; int stride, K32, Fp, kidx;
    if (!isW2) {
        Fp = rem2 >> 4; kidx = rem2 & 15;   // Fp 0..31, kidx 0..15
        stride = H_; K32 = 16; base = W1; dstB = W1S;
    } else {
        Fp = rem2 >> 5; kidx = rem2 & 31;   // Fp 0..15, kidx 0..31
        stride = D_; K32 = 32; base = W2; dstB = W2S;
    }
    const int k = kidx * 32 + g * 8;
    const float* src = base + ((size_t)e << 19) + (size_t)k * stride + Fp * 32 + m;
    unsigned short* dst0 = dstB + ((size_t)e << 19)
                         + ((size_t)(2 * Fp * K32 + kidx) << 9) + lane * 8;
    unsigned short* dst1 = dst0 + ((size_t)K32 << 9);
    float v0[8], v1[8];
#pragma unroll
    for (int j = 0; j < 8; ++j) {
        v0[j] = src[(size_t)j * stride];
        v1[j] = src[(size_t)j * stride + 16];
    }
    union { unsigned short u[8]; uint4 q; } p0, p1;
#pragma unroll
    for (int j = 0; j < 8; ++j) { p0.u[j] = f2bf(v0[j]); p1.u[j] = f2bf(v1[j]); }
    *(uint4*)dst0 = p0.q;
    *(uint4*)dst1 = p1.q;
}

// ---- build1: 16 blocks x 256 thr, one token each. Per-block histogram +
//      within-block exclusive offsets (deterministic, token-index order). ----
__global__ __launch_bounds__(256) void build1_kernel(
    const uchar2* __restrict__ tokE,
    ushort2* __restrict__ locs, int* __restrict__ blockCnt)
{
    __shared__ int waveTot[4][E_];
    const int tid = threadIdx.x, lane = tid & 63, wave = tid >> 6;
    const int t = blockIdx.x * 256 + tid;
    const uchar2 ee = tokE[t];
    int scan_pre[E_];   // static-indexed only (unrolled loops)
#pragma unroll
    for (int e = 0; e < E_; ++e) {
        const int orig = (ee.x == e) + (ee.y == e);   // 0 or 1
        int v = orig;
#pragma unroll
        for (int off = 1; off < 64; off <<= 1) {
            const int o = __shfl_up(v, off, 64);
            if (lane >= off) v += o;
        }
        scan_pre[e] = v - orig;
        if (lane == 63) waveTot[wave][e] = v;
    }
    __syncthreads();
    int loc0 = 0, loc1 = 0;
#pragma unroll
    for (int e = 0; e < E_; ++e) {
        int add = 0;
#pragma unroll
        for (int w = 0; w < 4; ++w) if (w < wave) add += waveTot[w][e];
        const int pre = scan_pre[e] + add;
        if (ee.x == e) loc0 = pre;
        if (ee.y == e) loc1 = pre;
    }
    if (tid < E_)
        blockCnt[blockIdx.x * E_ + tid] =
            waveTot[0][tid] + waveTot[1][tid] + waveTot[2][tid] + waveTot[3][tid];
    if (ee.x != 255)
        locs[t] = make_ushort2((unsigned short)loc0, (unsigned short)loc1);
}

// ---- build2: 16 blocks x 256 thr. WITHIN-EXPERT bases from blockCnt, scatter.
//      (R8 bug: added cross-expert cum to the slot; lists is e*NT_+slot with
//       slot strictly within-expert. Fixed: base = sum of earlier blocks only.)
__global__ __launch_bounds__(256) void build2_kernel(
    const uchar2* __restrict__ tokE, const float2* __restrict__ tokG,
    const ushort2* __restrict__ locs, const int* __restrict__ blockCnt,
    int* __restrict__ counts, int* __restrict__ lists, float* __restrict__ gvals)
{
    __shared__ int bc[16][E_];
    const int tid = threadIdx.x;
    const int b = blockIdx.x;
    if (tid < 16 * E_) bc[tid >> 3][tid & 7] = blockCnt[tid];
    __syncthreads();
    if (b == 0 && tid < E_) {
        int s = 0;
#pragma unroll
        for (int bb = 0; bb < 16; ++bb) s += bc[bb][tid];
        counts[tid] = s;
    }
    const int t = b * 256 + tid;
    const uchar2 ee = tokE[t];
    if (ee.x == 255) return;
    int base0 = 0, base1 = 0;
#pragma unroll
    for (int e = 0; e < E_; ++e) {
        int boff = 0;
#pragma unroll
        for (int bb = 0; bb < 16; ++bb) if (bb < b) boff += bc[bb][e];
        if (ee.x == e) base0 = boff;
        if (ee.y == e) base1 = boff;
    }
    const ushort2 lc = locs[t];
    const float2 gg = tokG[t];
    const int s0 = ee.x * NT_ + base0 + lc.x;
    const int s1 = ee.y * NT_ + base1 + lc.y;
    lists[s0] = t; gvals[s0] = gg.x;
    lists[s1] = t; gvals[s1] = gg.y;
}

// ---- stage1: H[slot][h] = relu(Xbf[tok] @ W1 + b1), streaming MFMA ----
// bid = (ti*4+nb)*8 + e  -> expert e pinned to XCD (bid%8); grid = MAXTILE*4*8
__global__ __launch_bounds__(256) void stage1_kernel(
    const unsigned short* __restrict__ xbf,
    const unsigned short* __restrict__ W1S, const float* __restrict__ b1,
    const int* __restrict__ counts, const int* __restrict__ lists,
    unsigned short* __restrict__ Hbuf)
{
    const int bid = blockIdx.x;
    const int e  = bid & 7;
    const int nb = (bid >> 3) & 3;
    const int ti = bid >> 5;
    const int n_e = counts[e];
    const int t0 = ti << 5;
    if (t0 >= n_e) return;
    int off = 0;
#pragma unroll
    for (int i = 0; i < E_; ++i) if (i < e) off += counts[i];
    const int mact = min(32, n_e - t0);
    __shared__ int tks[32];
    const int tid = threadIdx.x;
    if (tid < 32) tks[tid] = lists[e * NT_ + t0 + min(tid, mact - 1)];
    __syncthreads();

    const int wave = tid >> 6, lane = tid & 63, m = lane & 15, g = lane >> 4;
    const int colbase = nb * 256 + wave * 64;

    const unsigned short* a0p = xbf + ((size_t)tks[m] << 9) + (g << 3);
    const unsigned short* a1p = xbf + ((size_t)tks[16 + m] << 9) + (g << 3);
    const unsigned short* Bb = W1S + ((size_t)e << 19)
                             + ((size_t)(nb * 16 + wave * 4) << 13) + (lane << 3);

    f32x4 acc[2][4];
#pragma unroll
    for (int i = 0; i < 2; ++i)
#pragma unroll
        for (int f = 0; f < 4; ++f) acc[i][f] = (f32x4){0.f, 0.f, 0.f, 0.f};

#pragma unroll 2
    for (int kk = 0; kk < 16; ++kk) {
        const short8v a0 = *(const short8v*)(a0p + (kk << 5));
        const short8v a1 = *(const short8v*)(a1p + (kk << 5));
        const short8v b0  = *(const short8v*)(Bb + (kk << 9));
        const short8v b1v = *(const short8v*)(Bb + (1 << 13) + (kk << 9));
        const short8v b2v = *(const short8v*)(Bb + (2 << 13) + (kk << 9));
        const short8v b3  = *(const short8v*)(Bb + (3 << 13) + (kk << 9));
        acc[0][0] = __builtin_amdgcn_mfma_f32_16x16x32_bf16(a0, b0,  acc[0][0], 0, 0, 0);
        acc[1][0] = __builtin_amdgcn_mfma_f32_16x16x32_bf16(a1, b0,  acc[1][0], 0, 0, 0);
        acc[0][1] = __builtin_amdgcn_mfma_f32_16x16x32_bf16(a0, b1v, acc[0][1], 0, 0, 0);
        acc[1][1] = __builtin_amdgcn_mfma_f32_16x16x32_bf16(a1, b1v, acc[1][1], 0, 0, 0);
        acc[0][2] = __builtin_amdgcn_mfma_f32_16x16x32_bf16(a0, b2v, acc[0][2], 0, 0, 0);
        acc[1][2] = __builtin_amdgcn_mfma_f32_16x16x32_bf16(a1, b2v, acc[1][2], 0, 0, 0);
        acc[0][3] = __builtin_amdgcn_mfma_f32_16x16x32_bf16(a0, b3,  acc[0][3], 0, 0, 0);
        acc[1][3] = __builtin_amdgcn_mfma_f32_16x16x32_bf16(a1, b3,  acc[1][3], 0, 0, 0);
    }

#pragma unroll
    for (int f = 0; f < 4; ++f) {
        const int col = colbase + f * 16 + m;
        const float bias = b1[(e << 10) + col];
#pragma unroll
        for (int i = 0; i < 2; ++i)
#pragma unroll
            for (int r = 0; r < 4; ++r) {
                const int row = i * 16 + g * 4 + r;
                if (row < mact)
                    Hbuf[((size_t)(off + t0 + row) << 10) + col] =
                        f2bf(fmaxf(acc[i][f][r] + bias, 0.f));
            }
    }
}

// ---- stage2: out[tok] += gate * (H[slot] @ W2 + b2), streaming MFMA ----
// bid = (ti*2+nb)*8 + e; grid = MAXTILE*2*8
__global__ __launch_bounds__(256) void stage2_kernel(
    const unsigned short* __restrict__ Hbuf,
    const unsigned short* __restrict__ W2S, const float* __restrict__ b2,
    const int* __restrict__ counts, const int* __restrict__ lists,
    const float* __restrict__ gvals, float* __restrict__ out)
{
    const int bid = blockIdx.x;
    const int e  = bid & 7;
    const int nb = (bid >> 3) & 1;
    const int ti = bid >> 4;
    const int n_e = counts[e];
    const int t0 = ti << 5;
    if (t0 >= n_e) return;
    int off = 0;
#pragma unroll
    for (int i = 0; i < E_; ++i) if (i < e) off += counts[i];
    const int mact = min(32, n_e - t0);
    __shared__ int tks[32];
    __shared__ float gsh[32];
    const int tid = threadIdx.x;
    if (tid < 32) {
        const int idx = min(tid, mact - 1);
        tks[tid] = lists[e * NT_ + t0 + idx];
        gsh[tid] = gvals[e * NT_ + t0 + idx];
    }
    __syncthreads();

    const int wave = tid >> 6, lane = tid & 63, m = lane & 15, g = lane >> 4;
    const int colbase = nb * 256 + wave * 64;

    const unsigned short* a0p = Hbuf + ((size_t)(off + t0 + m) << 10) + (g << 3);
    const unsigned short* a1p = Hbuf + ((size_t)(off + t0 + 16 + m) << 10) + (g << 3);
    const unsigned short* Bb = W2S + ((size_t)e << 19)
                             + ((size_t)(nb * 16 + wave * 4) << 14) + (lane << 3);

    f32x4 acc[2][4];
#pragma unroll
    for (int i = 0; i < 2; ++i)
#pragma unroll
        for (int f = 0; f < 4; ++f) acc[i][f] = (f32x4){0.f, 0.f, 0.f, 0.f};

#pragma unroll 2
    for (int kk = 0; kk < 32; ++kk) {
        const short8v a0 = *(const short8v*)(a0p + (kk << 5));
        const short8v a1 = *(const short8v*)(a1p + (kk << 5));
        const short8v b0  = *(const short8v*)(Bb + (kk << 9));
        const short8v b1v = *(const short8v*)(Bb + (1 << 14) + (kk << 9));
        const short8v b2v = *(const short8v*)(Bb + (2 << 14) + (kk << 9));
        const short8v b3  = *(const short8v*)(Bb + (3 << 14) + (kk << 9));
        acc[0][0] = __builtin_amdgcn_mfma_f32_16x16x32_bf16(a0, b0,  acc[0][0], 0, 0, 0);
        acc[1][0] = __builtin_amdgcn_mfma_f32_16x16x32_bf16(a1, b0,  acc[1][0], 0, 0, 0);
        acc[0][1] = __builtin_amdgcn_mfma_f32_16x16x32_bf16(a0, b1v, acc[0][1], 0, 0, 0);
        acc[1][1] = __builtin_amdgcn_mfma_f32_16x16x32_bf16(a1, b1v, acc[1][1], 0, 0, 0);
        acc[0][2] = __builtin_amdgcn_mfma_f32_16x16x32_bf16(a0, b2v, acc[0][2], 0, 0, 0);
        acc[1][2] = __builtin_amdgcn_mfma_f32_16x16x32_bf16(a1, b2v, acc[1][2], 0, 0, 0);
        acc[0][3] = __builtin_amdgcn_mfma_f32_16x16x32_bf16(a0, b3,  acc[0][3], 0, 0, 0);
        acc[1][3] = __builtin_amdgcn_mfma_f32_16x16x32_bf16(a1, b3,  acc[1][3], 0, 0, 0);
    }

#pragma unroll
    for (int f = 0; f < 4; ++f) {
        const int col = colbase + f * 16 + m;
        const float bias = b2[(e << 9) + col];
#pragma unroll
        for (int i = 0; i < 2; ++i)
#pragma unroll
            for (int r = 0; r < 4; ++r) {
                const int row = i * 16 + g * 4 + r;
                if (row < mact)
                    atomicAdd(out + ((size_t)tks[row] << 9) + col,
                              (acc[i][f][r] + bias) * gsh[row]);
            }
    }
}

// ======================= TIER B/C fallbacks =======================

__global__ __launch_bounds__(256) void gating_kernel(
    const float* __restrict__ x, const int* __restrict__ mask,
    const float* __restrict__ wg, int* __restrict__ counts,
    int* __restrict__ lists, float* __restrict__ gvals)
{
    const int wave = threadIdx.x >> 6;
    const int lane = threadIdx.x & 63;
    const int t = blockIdx.x * 4 + wave;
    const float* xr = x + (size_t)t * D_;
    float acc[E_];
#pragma unroll
    for (int e = 0; e < E_; ++e) acc[e] = 0.f;
    for (int d = lane; d < D_; d += 64) {
        const float xv = xr[d];
        const float* wr = wg + (size_t)d * E_;
#pragma unroll
        for (int e = 0; e < E_; ++e) acc[e] += xv * wr[e];
    }
#pragma unroll
    for (int e = 0; e < E_; ++e) {
        float v = acc[e];
#pragma unroll
        for (int off = 32; off > 0; off >>= 1) v += __shfl_down(v, off, 64);
        acc[e] = v;
    }
    if (lane == 0 && mask[t] != 0) {
        int i0 = 0; float v0 = acc[0];
#pragma unroll
        for (int e = 1; e < E_; ++e) if (acc[e] > v0) { v0 = acc[e]; i0 = e; }
        int i1 = -1; float v1 = -INFINITY;
#pragma unroll
        for (int e = 0; e < E_; ++e) if (e != i0 && acc[e] > v1) { v1 = acc[e]; i1 = e; }
        const float ex = __expf(v1 - v0);
        const float denom = 1.f + ex;
        const int p0 = atomicAdd(&counts[i0], 1);
        lists[i0 * NT_ + p0] = t; gvals[i0 * NT_ + p0] = 1.f / denom;
        const int p1 = atomicAdd(&counts[i1], 1);
        lists[i1 * NT_ + p1] = t; gvals[i1 * NT_ + p1] = ex / denom;
    }
}

__global__ __launch_bounds__(256) void init_out_kernel(
    const float* __restrict__ x, float* __restrict__ out)
{
    const size_t i = (size_t)blockIdx.x * blockDim.x + threadIdx.x;
    ((float4*)out)[i] = ((const float4*)x)[i];
}

__global__ __launch_bounds__(256) void transpose_cvt(
    const float* __restrict__ src, unsigned short* __restrict__ dst, int R, int C)
{
    __shared__ unsigned short t[64][72];
    const float* s = src + (size_t)blockIdx.z * R * C;
    unsigned short* d = dst + (size_t)blockIdx.z * R * C;
    const int r0 = blockIdx.y * 64, c0 = blockIdx.x * 64;
    const int tc = threadIdx.x & 63;
    const int tr = threadIdx.x >> 6;
#pragma unroll
    for (int i = 0; i < 16; ++i) {
        const int r = tr + i * 4;
        t[r][tc] = f2bf(s[(size_t)(r0 + r) * C + c0 + tc]);
    }
    __syncthreads();
    const int c = threadIdx.x >> 2;
    const int ch = threadIdx.x & 3;
#pragma unroll
    for (int half = 0; half < 2; ++half) {
        union { unsigned short u[8]; uint4 v; } p;
#pragma unroll
        for (int k = 0; k < 8; ++k) p.u[k] = t[ch * 16 + half * 8 + k][c];
        *(uint4*)(d + (size_t)(c0 + c) * R + r0 + ch * 16 + half * 8) = p.v;
    }
}

__global__ __launch_bounds__(256) void expert_mfma(
    const float* __restrict__ x,
    const unsigned short* __restrict__ W1T, const float* __restrict__ b1,
    const unsigned short* __restrict__ W2T, const float* __restrict__ b2,
    const int* __restrict__ counts, const int* __restrict__ lists,
    const float* __restrict__ gvals, float* __restrict__ out)
{
    __shared__ unsigned short Xs[TM * D_];
    __shared__ unsigned short Hs[TM * H_];
    __shared__ int   tks[TM];
    __shared__ float gs[TM];

    const int bi = blockIdx.x;
    const int e = bi & 7;
    const int t0 = (bi >> 3) * TM;
    const int n = counts[e];
    if (t0 >= n) return;
    const int tid = threadIdx.x;
    const int mact = min(TM, n - t0);
    const int wave = tid >> 6;
    const int lane = tid & 63;
    const int m = lane & 15;
    const int g = lane >> 4;
    char* XsC = (char*)Xs;
    char* HsC = (char*)Hs;

    if (tid < TM) {
        if (tid < mact) {
            tks[tid] = lists[e * NT_ + t0 + tid];
            gs[tid]  = gvals[e * NT_ + t0 + tid];
        } else { tks[tid] = 0; gs[tid] = 0.f; }
    }
    __syncthreads();

    for (int idx = tid; idx < TM * (D_ / 8); idx += 256) {
        const int mm = idx >> 6;
        const int c8 = idx & 63;
        union { unsigned short u[8]; uint4 v; } p;
        if (mm < mact) {
            const float4* xr = (const float4*)(x + (size_t)tks[mm] * D_);
            const float4 v0 = xr[c8 * 2], v1 = xr[c8 * 2 + 1];
            p.u[0]=f2bf(v0.x); p.u[1]=f2bf(v0.y); p.u[2]=f2bf(v0.z); p.u[3]=f2bf(v0.w);
            p.u[4]=f2bf(v1.x); p.u[5]=f2bf(v1.y); p.u[6]=f2bf(v1.z); p.u[7]=f2bf(v1.w);
        } else {
            p.v = make_uint4(0, 0, 0, 0);
        }
        const int off = mm * (D_ * 2) + c8 * 16;
        *(uint4*)(XsC + (off ^ ((mm & 7) << 4))) = p.v;
    }
    __syncthreads();

    const int nbase = wave * 256;
    f32x4 acc1[16];
#pragma unroll
    for (int f = 0; f < 16; ++f) acc1[f] = (f32x4){0.f, 0.f, 0.f, 0.f};

    for (int k0 = 0; k0 < D_; k0 += 32) {
        const int aoff = m * (D_ * 2) + k0 * 2 + g * 16;
        const short8v a = *(const short8v*)(XsC + (aoff ^ ((m & 7) << 4)));
#pragma unroll
        for (int f = 0; f < 16; ++f) {
            const unsigned short* bp = W1T + (((size_t)(e << 10) + nbase + f * 16 + m) << 9) + k0 + g * 8;
            const short8v b = *(const short8v*)bp;
            acc1[f] = __builtin_amdgcn_mfma_f32_16x16x32_bf16(a, b, acc1[f], 0, 0, 0);
        }
    }
#pragma unroll
    for (int f = 0; f < 16; ++f) {
        const int nn = nbase + f * 16 + m;
        const float bias = b1[(e << 10) + nn];
#pragma unroll
        for (int r = 0; r < 4; ++r) {
            const int mm = g * 4 + r;
            const unsigned short hv = f2bf(fmaxf(acc1[f][r] + bias, 0.f));
            const int off = mm * (H_ * 2) + nn * 2;
            *(unsigned short*)(HsC + (off ^ ((mm & 7) << 4))) = hv;
        }
    }
    __syncthreads();

    const int obase = wave * 128;
    f32x4 acc2[8];
#pragma unroll
    for (int f = 0; f < 8; ++f) acc2[f] = (f32x4){0.f, 0.f, 0.f, 0.f};

    for (int k0 = 0; k0 < H_; k0 += 32) {
        const int aoff = m * (H_ * 2) + k0 * 2 + g * 16;
        const short8v a = *(const short8v*)(HsC + (aoff ^ ((m & 7) << 4)));
#pragma unroll
        for (int f = 0; f < 8; ++f) {
            const unsigned short* bp = W2T + (((size_t)(e << 9) + obase + f * 16 + m) << 10) + k0 + g * 8;
            const short8v b = *(const short8v*)bp;
            acc2[f] = __builtin_amdgcn_mfma_f32_16x16x32_bf16(a, b, acc2[f], 0, 0, 0);
        }
    }
#pragma unroll
    for (int f = 0; f < 8; ++f) {
        const int o = obase + f * 16 + m;
        const float bias = b2[(e << 9) + o];
#pragma unroll
        for (int r = 0; r < 4; ++r) {
            const int mm = g * 4 + r;
            const float gv = gs[mm];
            if (gv != 0.f)
                atomicAdd(out + (size_t)tks[mm] * D_ + o, (acc2[f][r] + bias) * gv);
        }
    }
}

__global__ __launch_bounds__(256) void expert_fp32(
    const float* __restrict__ x,
    const float* __restrict__ W1, const float* __restrict__ b1,
    const float* __restrict__ W2, const float* __restrict__ b2,
    const int* __restrict__ counts, const int* __restrict__ lists,
    const float* __restrict__ gvals, float* __restrict__ out)
{
    __shared__ float Xs[TM][D_];
    __shared__ float Hs[TM][H_];
    __shared__ int   tks[TM];
    __shared__ float gs[TM];

    const int e  = blockIdx.y;
    const int n  = counts[e];
    const int t0 = blockIdx.x * TM;
    if (t0 >= n) return;
    const int tid  = threadIdx.x;
    const int mact = min(TM, n - t0);

    if (tid < TM) {
        if (tid < mact) {
            tks[tid] = lists[e * NT_ + t0 + tid];
            gs[tid]  = gvals[e * NT_ + t0 + tid];
        } else { tks[tid] = 0; gs[tid] = 0.f; }
    }
    __syncthreads();
    for (int idx = tid; idx < TM * (D_ / 4); idx += 256) {
        const int mm = idx >> 7, c = idx & 127;
        float4 v = make_float4(0.f, 0.f, 0.f, 0.f);
        if (mm < mact) v = ((const float4*)(x + (size_t)tks[mm] * D_))[c];
        ((float4*)&Xs[mm][0])[c] = v;
    }
    __syncthreads();
    const float* W1e = W1 + (size_t)e * D_ * H_;
    float acc[4][TM];
#pragma unroll
    for (int jj = 0; jj < 4; ++jj)
#pragma unroll
        for (int mm = 0; mm < TM; ++mm) acc[jj][mm] = 0.f;
    for (int d4 = 0; d4 < D_ / 4; ++d4) {
        float w[4][4];
#pragma unroll
        for (int dd = 0; dd < 4; ++dd) {
            const float* wp = W1e + (size_t)(d4 * 4 + dd) * H_ + tid;
#pragma unroll
            for (int jj = 0; jj < 4; ++jj) w[dd][jj] = wp[jj * 256];
        }
#pragma unroll
        for (int mm = 0; mm < TM; ++mm) {
            const float4 xv = ((const float4*)&Xs[mm][0])[d4];
            const float* xp = &xv.x;
#pragma unroll
            for (int dd = 0; dd < 4; ++dd)
#pragma unroll
                for (int jj = 0; jj < 4; ++jj)
                    acc[jj][mm] = fmaf(xp[dd], w[dd][jj], acc[jj][mm]);
        }
    }
#pragma unroll
    for (int jj = 0; jj < 4; ++jj) {
        const int j = jj * 256 + tid;
        const float bv = b1[e * H_ + j];
#pragma unroll
        for (int mm = 0; mm < TM; ++mm) Hs[mm][j] = fmaxf(acc[jj][mm] + bv, 0.f);
    }
    __syncthreads();
    const float* W2e = W2 + (size_t)e * H_ * D_;
    float acc2[2][TM];
#pragma unroll
    for (int oo = 0; oo < 2; ++oo)
#pragma unroll
        for (int mm = 0; mm < TM; ++mm) acc2[oo][mm] = 0.f;
    for (int j4 = 0; j4 < H_ / 4; ++j4) {
        float w[4][2];
#pragma unroll
        for (int dd = 0; dd < 4; ++dd) {
            const float* wp = W2e + (size_t)(j4 * 4 + dd) * D_ + tid;
#pragma unroll
            for (int oo = 0; oo < 2; ++oo) w[dd][oo] = wp[oo * 256];
        }
#pragma unroll
        for (int mm = 0; mm < TM; ++mm) {
            const float4 hv = ((const float4*)&Hs[mm][0])[j4];
            const float* hp = &hv.x;
#pragma unroll
            for (int dd = 0; dd < 4; ++dd)
#pragma unroll
                for (int oo = 0; oo < 2; ++oo)
                    acc2[oo][mm] = fmaf(hp[dd], w[dd][oo], acc2[oo][mm]);
        }
    }
#pragma unroll
    for (int oo = 0; oo < 2; ++oo) {
        const int o = oo * 256 + tid;
        const float bv = b2[e * D_ + o];
        for (int mm = 0; mm < mact; ++mm)
            atomicAdd(out + (size_t)tks[mm] * D_ + o, (acc2[oo][mm] + bv) * gs[mm]);
    }
}

// ======================= host launcher =======================

extern "C" void kernel_launch(void* const* d_in, const int* in_sizes, int n_in,
                              void* d_out, int out_size, void* d_ws, size_t ws_size,
                              hipStream_t stream)
{
    const float* x    = (const float*)d_in[0];
    const int*   mask = (const int*)d_in[1];
    const float* wg   = (const float*)d_in[2];
    const float* W1   = (const float*)d_in[3];
    const float* b1   = (const float*)d_in[4];
    const float* W2   = (const float*)d_in[5];
    const float* b2   = (const float*)d_in[6];
    float* out = (float*)d_out;

    char* ws = (char*)d_ws;
    int*   counts = (int*)ws;                       // 32 B
    int*   lists  = (int*)(ws + 256);               // 128 KB
    float* gvals  = (float*)(ws + 256 + 131072);    // 128 KB

    // Tier A layout
    uchar2* tokE = (uchar2*)(ws + 0x48000);                             // 8 KB
    float2* tokG = (float2*)(ws + 0x50000);                             // 32 KB
    ushort2* locs = (ushort2*)(ws + 0x58000);                           // 16 KB
    int* blockCnt = (int*)(ws + 0x5C000);                               // 512 B
    unsigned short* xbf  = (unsigned short*)(ws + 0x60000);             // 4 MB
    unsigned short* W1Sa = (unsigned short*)(ws + 0x480000);            // 8 MB
    unsigned short* W2Sa = (unsigned short*)(ws + 0xC80000);            // 8 MB
    unsigned short* Hbuf = (unsigned short*)(ws + 0x1480000);           // 16.5 MB
    const size_t needA = 0x1480000 + (size_t)8448 * 1024 * 2;           // ~38.8 MB

    const size_t wt_bytes = (size_t)E_ * D_ * H_ * 2;
    const size_t needB = 524288 + 2 * wt_bytes;                         // ~17.3 MB

    if (ws_size >= needA) {
        prep_fused<<<3072, 256, 0, stream>>>(x, mask, wg, W1, W2,
                                             out, xbf, tokE, tokG, W1Sa, W2Sa);
        build1_kernel<<<16, 256, 0, stream>>>(tokE, locs, blockCnt);
        build2_kernel<<<16, 256, 0, stream>>>(tokE, tokG, locs, blockCnt,
                                              counts, lists, gvals);
        stage1_kernel<<<MAXTILE * 4 * 8, 256, 0, stream>>>(xbf, W1Sa, b1, counts, lists, Hbuf);
        stage2_kernel<<<MAXTILE * 2 * 8, 256, 0, stream>>>(Hbuf, W2Sa, b2, counts, lists, gvals, out);
    } else if (ws_size >= needB) {
        unsigned short* W1T = (unsigned short*)(ws + 524288);
        unsigned short* W2T = (unsigned short*)(ws + 524288 + wt_bytes);
        hipMemsetAsync(counts, 0, E_ * sizeof(int), stream);
        gating_kernel<<<NT_ / 4, 256, 0, stream>>>(x, mask, wg, counts, lists, gvals);
        init_out_kernel<<<(NT_ * D_) / 4 / 256, 256, 0, stream>>>(x, out);
        transpose_cvt<<<dim3(H_ / 64, D_ / 64, E_), 256, 0, stream>>>(W1, W1T, D_, H_);
        transpose_cvt<<<dim3(D_ / 64, H_ / 64, E_), 256, 0, stream>>>(W2, W2T, H_, D_);
        expert_mfma<<<(NT_ / TM) * E_, 256, 0, stream>>>(x, W1T, b1, W2T, b2,
                                                         counts, lists, gvals, out);
    } else {
        hipMemsetAsync(counts, 0, E_ * sizeof(int), stream);
        gating_kernel<<<NT_ / 4, 256, 0, stream>>>(x, mask, wg, counts, lists, gvals);
        init_out_kernel<<<(NT_ * D_) / 4 / 256, 256, 0, stream>>>(x, out);
        expert_fp32<<<dim3(NT_ / TM, E_), 256, 0, stream>>>(x, W1, b1, W2, b2,
                                                            counts, lists, gvals, out);
    }
}